// Round 10
// baseline (260.247 us; speedup 1.0000x reference)
//
#include <hip/hip_runtime.h>
#include <cstdint>
#include <cstddef>

// ---------- types / helpers ----------
typedef float f32x4 __attribute__((ext_vector_type(4)));
typedef __bf16 bf16x8 __attribute__((ext_vector_type(8)));

__device__ __forceinline__ float b2f(unsigned short u) {
    union { unsigned int i; float f; } z; z.i = ((unsigned int)u) << 16; return z.f;
}
__device__ __forceinline__ unsigned short f2b(float f) {
    union { float f; unsigned int i; } z; z.f = f;
    unsigned int x = z.i;
    return (unsigned short)((x + 0x7FFFu + ((x >> 16) & 1u)) >> 16);
}

static constexpr int C = 128;
static constexpr int NP = 16384;      // H*W
static constexpr int NH = 8;

#define SWZ(n) ((((n) ^ ((n) >> 3)) & 7) << 4)

// ---------- weight pack: fp32 -> bf16 (seg 3 pre-scaled by LN1 gamma) ----------
struct Ptr11 { const float* p[11]; };
__constant__ int kWN[11]   = {128, 128, 8, 49152, 3456, 16384, 128, 128, 65536, 4608, 32768};
__constant__ int kWOff[11] = {0, 128, 256, 272, 49424, 52880, 69264, 69392, 69520, 135056, 139664};
static constexpr int kWTotal = 172432;

__global__ __launch_bounds__(256)
void cvt_w_kernel(Ptr11 P, unsigned short* __restrict__ dst)
{
    int seg = blockIdx.y;
    int n = kWN[seg];
    int i = blockIdx.x * 256 + threadIdx.x;
    if (i >= n) return;
    float v = P.p[seg][i];
    if (seg == 3) v *= P.p[0][i & 127];     // W~ = qkv_p_w * ln1_GAMMA
    dst[kWOff[seg] + i] = f2b(v);
}

// ---------- S[o] = sum_c bf16(W~[o,c]);  K[o] = sum_c W[o,c]*beta[c] ----------
__global__ __launch_bounds__(128)
void prep_lnw_kernel(const float* __restrict__ w,
                     const float* __restrict__ g,
                     const float* __restrict__ bb,
                     float* __restrict__ Saux, float* __restrict__ Kaux)
{
    int o = blockIdx.x * 128 + threadIdx.x;
    if (o >= 384) return;
    float s = 0.f, k = 0.f;
    for (int c = 0; c < 128; ++c) {
        float wv = w[o * 128 + c];
        s += b2f(f2b(wv * g[c]));
        k += wv * bb[c];
    }
    Saux[o] = s; Kaux[o] = k;
}

// ---------- shared dwconv3 row helper: 8 px, halos via width-16 shuffles ----------
__device__ __forceinline__ void dw8(const unsigned short* base, int y, int xi,
                                    const float* wr, float* o)
{
    uint4 rv0 = uint4{0,0,0,0}, rv1, rv2 = uint4{0,0,0,0};
    if (y > 0)   rv0 = *(const uint4*)(base - 128);
    rv1 = *(const uint4*)(base);
    if (y < 127) rv2 = *(const uint4*)(base + 128);
    uint4 rows[3] = {rv0, rv1, rv2};
    #pragma unroll
    for (int j = 0; j < 8; ++j) o[j] = 0.f;
    #pragma unroll
    for (int r = 0; r < 3; ++r) {
        union { uint4 v; unsigned short u[8]; } cv; cv.v = rows[r];
        int lh = __shfl_up((int)cv.u[7], 1, 16);
        int rh = __shfl_down((int)cv.u[0], 1, 16);
        float p[10];
        p[0] = (xi > 0)   ? b2f((unsigned short)lh) : 0.f;
        p[9] = (xi < 120) ? b2f((unsigned short)rh) : 0.f;
        #pragma unroll
        for (int j = 0; j < 8; ++j) p[j + 1] = b2f(cv.u[j]);
        #pragma unroll
        for (int j = 0; j < 8; ++j)
            o[j] += wr[r * 3] * p[j] + wr[r * 3 + 1] * p[j + 1] + wr[r * 3 + 2] * p[j + 2];
    }
}

// ============================================================
// LN-folded qkv GEMM, 64-pixel tile. Epilogue: LDS transpose -> uint4 stores.
// ============================================================
__global__ __launch_bounds__(256)
void lngemm_fused(const float* __restrict__ x,            // (nb, C, NP) fp32
                  const unsigned short* __restrict__ Wt,  // (384,128) bf16 = bf16(W*gamma)
                  const float* __restrict__ Saux,
                  const float* __restrict__ Kaux,
                  unsigned short* __restrict__ Out)       // (nb,384,NP) bf16
{
    __shared__ unsigned short BsT[64 * 128];
    __shared__ unsigned short St[128 * 72];   // 128 co x 64 px, row 144B (9x16B)
    __shared__ float LSum[4][64], LSq[4][64], Mu[64], Rs[64];
    const int tid = threadIdx.x;
    const int b = blockIdx.y;
    const int n0 = blockIdx.x * 64;
    const int pxg = tid & 15;        // 4 px each
    const int cseg = tid >> 4;       // 16 groups x 8 ch
    const int lane = tid & 63;
    const float* xb = x + (size_t)b * C * NP + n0 + pxg * 4;
    char* p = (char*)BsT;

    // stage raw x -> bf16 LDS tile [n][k] (swizzled), accumulate stats
    f32x4 vs = f32x4{0.f,0.f,0.f,0.f}, vq = f32x4{0.f,0.f,0.f,0.f};
    {
        f32x4 hv[8];
        #pragma unroll
        for (int i = 0; i < 8; ++i) {
            f32x4 v = *(const f32x4*)(xb + (size_t)(cseg * 8 + i) * NP);
            hv[i] = v; vs += v; vq += v * v;
        }
        #pragma unroll
        for (int j = 0; j < 4; ++j) {
            int n = pxg * 4 + j;
            union { uint4 v; unsigned short u[8]; } o;
            #pragma unroll
            for (int i = 0; i < 8; ++i) o.u[i] = f2b(hv[i][j]);
            *(uint4*)(p + ((n * 256 + cseg * 16) ^ SWZ(n))) = o.v;
        }
    }
    #pragma unroll
    for (int j = 0; j < 4; ++j) {
        vs[j] += __shfl_xor(vs[j], 16, 64); vq[j] += __shfl_xor(vq[j], 16, 64);
        vs[j] += __shfl_xor(vs[j], 32, 64); vq[j] += __shfl_xor(vq[j], 32, 64);
    }
    if (lane < 16) {
        int wv = tid >> 6;
        #pragma unroll
        for (int j = 0; j < 4; ++j) { LSum[wv][pxg * 4 + j] = vs[j]; LSq[wv][pxg * 4 + j] = vq[j]; }
    }
    __syncthreads();
    if (tid < 64) {
        float s = LSum[0][tid] + LSum[1][tid] + LSum[2][tid] + LSum[3][tid];
        float q = LSq[0][tid] + LSq[1][tid] + LSq[2][tid] + LSq[3][tid];
        float mu = s * (1.f / 128.f);
        float var = q * (1.f / 128.f) - mu * mu;
        Mu[tid] = mu; Rs[tid] = rsqrtf(fmaxf(var, 0.f) + 1e-5f);
    }
    __syncthreads();

    const int wid = tid >> 6;
    const int ln16 = lane & 15, quad = lane >> 4;
    const int wy = wid >> 1, wx = wid & 1;
    int rbase[2], swz[2];
    #pragma unroll
    for (int nt = 0; nt < 2; ++nt) {
        int n = wx * 32 + nt * 16 + ln16;
        rbase[nt] = n * 256 + quad * 16;
        swz[nt] = SWZ(n);
    }
    size_t ob = (size_t)b * 384 * NP;
    #pragma unroll
    for (int cc = 0; cc < 3; ++cc) {
        const unsigned short* Wc = Wt + (size_t)cc * 128 * 128;
        f32x4 acc[4][2];
        #pragma unroll
        for (int i = 0; i < 4; ++i)
            #pragma unroll
            for (int j = 0; j < 2; ++j) acc[i][j] = f32x4{0.f, 0.f, 0.f, 0.f};

        #pragma unroll
        for (int k0 = 0; k0 < 128; k0 += 32) {
            bf16x8 afr[4], bfr[2];
            #pragma unroll
            for (int mt = 0; mt < 4; ++mt) {
                int m = wy * 64 + mt * 16 + ln16;
                uint4 v = *(const uint4*)(Wc + (size_t)m * 128 + k0 + quad * 8);
                afr[mt] = *(bf16x8*)&v;
            }
            #pragma unroll
            for (int nt = 0; nt < 2; ++nt) {
                uint4 v = *(const uint4*)(p + ((rbase[nt] + k0 * 2) ^ swz[nt]));
                bfr[nt] = *(bf16x8*)&v;
            }
            #pragma unroll
            for (int mt = 0; mt < 4; ++mt)
                #pragma unroll
                for (int nt = 0; nt < 2; ++nt)
                    acc[mt][nt] = __builtin_amdgcn_mfma_f32_16x16x32_bf16(
                        afr[mt], bfr[nt], acc[mt][nt], 0, 0, 0);
        }
        // epilogue: LN correction -> St[co][px] -> vectorized stores
        #pragma unroll
        for (int mt = 0; mt < 4; ++mt) {
            int col = wy * 64 + mt * 16 + quad * 4;     // co within chunk
            f32x4 S4 = *(const f32x4*)(Saux + cc * 128 + col);
            f32x4 K4 = *(const f32x4*)(Kaux + cc * 128 + col);
            #pragma unroll
            for (int nt = 0; nt < 2; ++nt) {
                int nn = wx * 32 + nt * 16 + ln16;
                float mu = Mu[nn], rs = Rs[nn];
                #pragma unroll
                for (int r = 0; r < 4; ++r)
                    St[(col + r) * 72 + nn] = f2b(rs * (acc[mt][nt][r] - mu * S4[r]) + K4[r]);
            }
        }
        __syncthreads();
        #pragma unroll
        for (int i = 0; i < 4; ++i) {
            int flat = tid + i * 256;        // 0..1023
            int row = flat >> 3;             // 0..127
            int g = flat & 7;                // 8-px group
            uint4 v = *(const uint4*)(&St[row * 72 + g * 8]);
            *(uint4*)(&Out[ob + (size_t)(cc * 128 + row) * NP + n0 + g * 8]) = v;
        }
        __syncthreads();
    }
}

// ============================================================
// Transposed+swizzled GEMM core with vectorized-store epilogue (g1).
// ============================================================
template <int COUT>
__device__ __forceinline__ void gemm_core_tr(
    const unsigned short* BsT,
    unsigned short* St,                        // [64*136]
    const unsigned short* __restrict__ W,      // (COUT, 128) bf16, row-major
    unsigned short* __restrict__ OutB,         // already + b*COUT*NP, channel-major
    int n0, int tid)
{
    const int lane = tid & 63;
    const int wid  = tid >> 6;
    const int ln16 = lane & 15, quad = lane >> 4;
    const int wy = wid >> 1, wx = wid & 1;
    const char* bs = (const char*)BsT;
    const int swz = (ln16 & 7) << 4;
    int rbase[4];
    #pragma unroll
    for (int nt = 0; nt < 4; ++nt) {
        int n = wx * 64 + nt * 16 + ln16;
        rbase[nt] = n * 256 + quad * 16;
    }

    for (int cc = 0; cc < COUT / 128; ++cc) {
        const int m0 = cc * 128;
        f32x4 acc[4][4];
        #pragma unroll
        for (int i = 0; i < 4; ++i)
            #pragma unroll
            for (int j = 0; j < 4; ++j) acc[i][j] = f32x4{0.f, 0.f, 0.f, 0.f};

        #pragma unroll
        for (int k0 = 0; k0 < 128; k0 += 32) {
            bf16x8 afr[4], bfr[4];
            #pragma unroll
            for (int mt = 0; mt < 4; ++mt) {
                int m = m0 + wy * 64 + mt * 16 + ln16;
                uint4 v = *(const uint4*)(W + (size_t)m * 128 + k0 + quad * 8);
                afr[mt] = *(bf16x8*)&v;
            }
            #pragma unroll
            for (int nt = 0; nt < 4; ++nt) {
                uint4 v = *(const uint4*)(bs + ((rbase[nt] + k0 * 2) ^ swz));
                bfr[nt] = *(bf16x8*)&v;
            }
            #pragma unroll
            for (int mt = 0; mt < 4; ++mt)
                #pragma unroll
                for (int nt = 0; nt < 4; ++nt)
                    acc[mt][nt] = __builtin_amdgcn_mfma_f32_16x16x32_bf16(
                        afr[mt], bfr[nt], acc[mt][nt], 0, 0, 0);
        }
        #pragma unroll
        for (int h = 0; h < 2; ++h) {
            if (wy == h) {
                #pragma unroll
                for (int mt = 0; mt < 4; ++mt) {
                    int lr0 = mt * 16 + quad * 4;
                    #pragma unroll
                    for (int nt = 0; nt < 4; ++nt) {
                        int nn = wx * 64 + nt * 16 + ln16;
                        #pragma unroll
                        for (int r = 0; r < 4; ++r)
                            St[(lr0 + r) * 136 + nn] = f2b(acc[mt][nt][r]);
                    }
                }
            }
            __syncthreads();
            #pragma unroll
            for (int i = 0; i < 4; ++i) {
                int flat = tid + i * 256;    // 0..1023
                int row = flat >> 4;         // 0..63
                int g = flat & 15;           // 8-px group (128 px)
                uint4 v = *(const uint4*)(&St[row * 136 + g * 8]);
                *(uint4*)(&OutB[(size_t)(m0 + h * 64 + row) * NP + n0 + g * 8]) = v;
            }
            __syncthreads();
        }
    }
}

// ---------- plain GEMM from PIXEL-MAJOR bf16 input (g1) ----------
template <int COUT>
__global__ __launch_bounds__(256)
void gemm_bf16t_kernel(const unsigned short* __restrict__ W,   // (COUT,128) bf16
                       const unsigned short* __restrict__ Xt,  // (nb, NP, 128) bf16
                       unsigned short* __restrict__ Out)       // (nb, COUT, NP) bf16
{
    __shared__ unsigned short BsT[128 * 128];
    __shared__ unsigned short St[64 * 136];
    const int tid = threadIdx.x;
    const int b = blockIdx.y;
    const int n0 = blockIdx.x * 128;
    const unsigned short* Xb = Xt + (size_t)b * NP * 128 + (size_t)n0 * 128;
    char* p = (char*)BsT;
    #pragma unroll
    for (int r = 0; r < 8; ++r) {
        int flat = tid + r * 256;
        int n = flat >> 4, ks = flat & 15;
        uint4 v = *(const uint4*)(Xb + (size_t)n * 128 + ks * 8);
        *(uint4*)(p + ((n * 256 + ks * 16) ^ ((n & 7) << 4))) = v;
    }
    __syncthreads();
    gemm_core_tr<COUT>(BsT, St, W, Out + (size_t)b * COUT * NP, n0, tid);
}

// ---------- FUSED dwconv3(q,k) + Gram partial + sumsq partial ----------
__global__ __launch_bounds__(256)
void dwqkgram_kernel(const unsigned short* __restrict__ big,   // (nb,384,NP)
                     const unsigned short* __restrict__ w9,    // qkv_d_w (384*9)
                     float* __restrict__ Spart,                // [bh][32][256]
                     float* __restrict__ Npart)                // [bh][32][32]
{
    __shared__ unsigned short qs_[16 * 520];
    __shared__ unsigned short ks_[16 * 520];
    __shared__ float Sred[4][256];
    const int h = blockIdx.x, b = blockIdx.y, sp = blockIdx.z;
    const int tid = threadIdx.x;
    const int wid = tid >> 6, lane = tid & 63;
    const int xi = (tid & 15) * 8;
    const int yr = (tid >> 4) & 3;       // row within slab
    const int y  = sp * 4 + yr;          // image row
    const int bh = b * NH + h;
    float* Np = Npart + ((size_t)bh * 32 + sp) * 32;

    #pragma unroll
    for (int p = 0; p < 4; ++p) {
        int qc = p * 4 + wid;            // local channel 0..15, one per wave
        #pragma unroll
        for (int s = 0; s < 2; ++s) {    // 0 = q, 1 = k
            int ch = s * 128 + h * 16 + qc;
            const unsigned short* base = big + ((size_t)b * 384 + ch) * NP + y * 128 + xi;
            float wr[9];
            #pragma unroll
            for (int i = 0; i < 9; ++i) wr[i] = b2f(w9[ch * 9 + i]);
            float o[8];
            dw8(base, y, xi, wr, o);
            union { uint4 v; unsigned short u[8]; } res;
            float ss = 0.f;
            #pragma unroll
            for (int j = 0; j < 8; ++j) {
                res.u[j] = f2b(o[j]);
                float vv = b2f(res.u[j]);
                ss += vv * vv;
            }
            unsigned short* tile = s ? ks_ : qs_;
            *(uint4*)(&tile[qc * 520 + yr * 128 + xi]) = res.v;
            #pragma unroll
            for (int od = 32; od > 0; od >>= 1) ss += __shfl_xor(ss, od, 64);
            if (lane == 0) Np[s * 16 + qc] = ss;
        }
    }
    __syncthreads();

    const int ln16 = lane & 15, quad = lane >> 4;
    f32x4 acc = f32x4{0.f, 0.f, 0.f, 0.f};
    #pragma unroll
    for (int i = 0; i < 4; ++i) {
        int off = wid * 128 + i * 32 + quad * 8;
        uint4 qv = *(const uint4*)(&qs_[ln16 * 520 + off]);
        uint4 kv = *(const uint4*)(&ks_[ln16 * 520 + off]);
        acc = __builtin_amdgcn_mfma_f32_16x16x32_bf16(*(bf16x8*)&qv, *(bf16x8*)&kv, acc, 0, 0, 0);
    }
    #pragma unroll
    for (int r = 0; r < 4; ++r) Sred[wid][(quad * 4 + r) * 16 + ln16] = acc[r];
    __syncthreads();
    float ssum = Sred[0][tid] + Sred[1][tid] + Sred[2][tid] + Sred[3][tid];
    Spart[((size_t)bh * 32 + sp) * 256 + tid] = ssum;
}

// ---------- softmax + fused W' = proj x blockdiag(P) ----------
__global__ __launch_bounds__(256)
void softwp_kernel(const float* __restrict__ Spart, const float* __restrict__ Npart,
                   const unsigned short* __restrict__ temp,
                   const unsigned short* __restrict__ proj,   // (128,128) bf16
                   unsigned short* __restrict__ W2)           // (nb,128,128) bf16
{
    __shared__ float Ps[256];
    int bh = blockIdx.x;
    int b = bh >> 3, h = bh & 7;
    int t = threadIdx.x;            // 256 = 16x16
    int dq = t >> 4, dk = t & 15;
    float sacc = 0.f;
    const float* Sp = Spart + (size_t)bh * 32 * 256;
    #pragma unroll
    for (int j = 0; j < 32; ++j) sacc += Sp[j * 256 + t];
    const float* Np = Npart + (size_t)bh * 32 * 32;
    float sq = 0.f, sk = 0.f;
    #pragma unroll
    for (int sp = 0; sp < 32; ++sp) { sq += Np[sp * 32 + dq]; sk += Np[sp * 32 + 16 + dk]; }
    float nq = fmaxf(sqrtf(sq), 1e-12f);
    float nk = fmaxf(sqrtf(sk), 1e-12f);
    float v = sacc / (nq * nk) * b2f(temp[h]);
    float m = v;
    #pragma unroll
    for (int o = 8; o > 0; o >>= 1) m = fmaxf(m, __shfl_xor(m, o, 16));
    float e = __expf(v - m);
    float s = e;
    #pragma unroll
    for (int o = 8; o > 0; o >>= 1) s += __shfl_xor(s, o, 16);
    Ps[t] = e / s;                 // P[dq][dk]
    __syncthreads();

    int co = t >> 1;
    int eo = (t & 1) * 8;
    union { uint4 v[2]; unsigned short u[16]; } pw;
    pw.v[0] = *(const uint4*)(proj + (size_t)co * 128 + h * 16);
    pw.v[1] = *(const uint4*)(proj + (size_t)co * 128 + h * 16 + 8);
    float prw[16];
    #pragma unroll
    for (int d = 0; d < 16; ++d) prw[d] = b2f(pw.u[d]);
    union { uint4 v; unsigned short u[8]; } o8;
    #pragma unroll
    for (int j = 0; j < 8; ++j) {
        int ee = eo + j;
        float s2 = 0.f;
        #pragma unroll
        for (int d = 0; d < 16; ++d) s2 += prw[d] * Ps[d * 16 + ee];
        o8.u[j] = f2b(s2);
    }
    *(uint4*)(W2 + ((size_t)b * 128 + co) * 128 + h * 16 + eo) = o8.v;
}

// ---------- proj' GEMM (W2[b] x dw-v computed IN-BLOCK) + residual + LN2 ----------
__global__ __launch_bounds__(256)
void projln_kernel(const unsigned short* __restrict__ W2,    // (nb,128,128) bf16
                   const unsigned short* __restrict__ big,   // (nb,384,NP) bf16
                   const unsigned short* __restrict__ w9,    // qkv_d_w
                   const float* __restrict__ Res,            // x fp32 (nb,128,NP)
                   unsigned short* __restrict__ Xmid,        // bf16 trunk out
                   const unsigned short* __restrict__ lg,
                   const unsigned short* __restrict__ lb,
                   unsigned short* __restrict__ Y2t)         // (nb, NP, 128) bf16
{
    __shared__ unsigned short Bs[128][130];
    __shared__ float RedS[2][128], RedQ[2][128], Mu[128], Rs[128];
    const int tid = threadIdx.x;
    const int b = blockIdx.y;
    const int y = blockIdx.x;            // image row
    const int n0 = y * 128;
    const unsigned short* Wb = W2 + (size_t)b * 16384;

    // ---- phase 0: dw-conv v -> Bs (8 passes x 16 channels) ----
    {
        const int xi = (tid & 15) * 8;
        const int crow = tid >> 4;       // 0..15
        #pragma unroll
        for (int p = 0; p < 8; ++p) {
            int c = p * 16 + crow;
            int ch = 256 + c;
            const unsigned short* base = big + ((size_t)b * 384 + ch) * NP + n0 + xi;
            float wr[9];
            #pragma unroll
            for (int i = 0; i < 9; ++i) wr[i] = b2f(w9[ch * 9 + i]);
            float o[8];
            dw8(base, y, xi, wr, o);
            union { uint4 v; unsigned int d[4]; unsigned short u[8]; } res;
            #pragma unroll
            for (int j = 0; j < 8; ++j) res.u[j] = f2b(o[j]);
            unsigned int* d = (unsigned int*)&Bs[c][xi];   // 4B-aligned (260B rows)
            d[0] = res.d[0]; d[1] = res.d[1]; d[2] = res.d[2]; d[3] = res.d[3];
        }
    }
    __syncthreads();

    const int lane = tid & 63, wid = tid >> 6;
    const int ln16 = lane & 15, quad = lane >> 4;
    const int wy = wid >> 1, wx = wid & 1;

    f32x4 acc[4][4];
    #pragma unroll
    for (int i = 0; i < 4; ++i)
        #pragma unroll
        for (int j = 0; j < 4; ++j) acc[i][j] = f32x4{0.f, 0.f, 0.f, 0.f};

    #pragma unroll
    for (int k0 = 0; k0 < 128; k0 += 32) {
        bf16x8 afr[4], bfr[4];
        #pragma unroll
        for (int mt = 0; mt < 4; ++mt) {
            int m = wy * 64 + mt * 16 + ln16;
            uint4 v = *(const uint4*)(Wb + (size_t)m * 128 + k0 + quad * 8);
            afr[mt] = *(bf16x8*)&v;
        }
        #pragma unroll
        for (int nt = 0; nt < 4; ++nt) {
            int n = wx * 64 + nt * 16 + ln16;
            union { bf16x8 v; unsigned short u[8]; } tmp;
            #pragma unroll
            for (int j = 0; j < 8; ++j) tmp.u[j] = Bs[k0 + quad * 8 + j][n];
            bfr[nt] = tmp.v;
        }
        #pragma unroll
        for (int mt = 0; mt < 4; ++mt)
            #pragma unroll
            for (int nt = 0; nt < 4; ++nt)
                acc[mt][nt] = __builtin_amdgcn_mfma_f32_16x16x32_bf16(
                    afr[mt], bfr[nt], acc[mt][nt], 0, 0, 0);
    }

    // pass A: trunk = Res + acc -> Xmid (bf16, channel-major), per-pixel partials
    size_t base = (size_t)b * 128 * NP;
    float ps[4] = {0.f, 0.f, 0.f, 0.f}, pq[4] = {0.f, 0.f, 0.f, 0.f};
    #pragma unroll
    for (int mt = 0; mt < 4; ++mt)
        #pragma unroll
        for (int nt = 0; nt < 4; ++nt) {
            int co0 = wy * 64 + mt * 16 + quad * 4;
            int n = n0 + wx * 64 + nt * 16 + ln16;
            #pragma unroll
            for (int r = 0; r < 4; ++r) {
                size_t idx = base + (size_t)(co0 + r) * NP + n;
                float tv = Res[idx] + acc[mt][nt][r];
                Xmid[idx] = f2b(tv);
                acc[mt][nt][r] = tv;
                ps[nt] += tv; pq[nt] += tv * tv;
            }
        }
    #pragma unroll
    for (int nt = 0; nt < 4; ++nt) {
        ps[nt] += __shfl_xor(ps[nt], 16, 64); ps[nt] += __shfl_xor(ps[nt], 32, 64);
        pq[nt] += __shfl_xor(pq[nt], 16, 64); pq[nt] += __shfl_xor(pq[nt], 32, 64);
    }
    if (quad == 0) {
        #pragma unroll
        for (int nt = 0; nt < 4; ++nt) {
            int nn = wx * 64 + nt * 16 + ln16;
            RedS[wy][nn] = ps[nt]; RedQ[wy][nn] = pq[nt];
        }
    }
    __syncthreads();
    if (tid < 128) {
        float s = RedS[0][tid] + RedS[1][tid];
        float q = RedQ[0][tid] + RedQ[1][tid];
        float mu = s * (1.f / 128.f);
        float var = q * (1.f / 128.f) - mu * mu;
        Mu[tid] = mu; Rs[tid] = rsqrtf(fmaxf(var, 0.f) + 1e-5f);
    }
    __syncthreads();

    // pass B: y2 = LN2(trunk) -> swizzled flat reuse of Bs as [n][c] (256B rows)
    char* p = (char*)Bs;
    #pragma unroll
    for (int mt = 0; mt < 4; ++mt) {
        int co0 = wy * 64 + mt * 16 + quad * 4;
        union { uint2 v; unsigned short u[4]; } gv, bv;
        gv.v = *(const uint2*)(lg + co0);
        bv.v = *(const uint2*)(lb + co0);
        float gw[4], bw[4];
        #pragma unroll
        for (int r = 0; r < 4; ++r) { gw[r] = b2f(gv.u[r]); bw[r] = b2f(bv.u[r]); }
        #pragma unroll
        for (int nt = 0; nt < 4; ++nt) {
            int nn = wx * 64 + nt * 16 + ln16;
            float mu = Mu[nn], rs = Rs[nn];
            union { uint2 v; unsigned short u[4]; } t2;
            #pragma unroll
            for (int r = 0; r < 4; ++r)
                t2.u[r] = f2b((acc[mt][nt][r] - mu) * rs * gw[r] + bw[r]);
            int addr = (nn * 256 + co0 * 2) ^ ((nn & 7) << 4);
            *(uint2*)(p + addr) = t2.v;
        }
    }
    __syncthreads();

    unsigned short* Yo = Y2t + (size_t)b * NP * 128 + (size_t)n0 * 128;
    #pragma unroll
    for (int r = 0; r < 8; ++r) {
        int flat = tid + r * 256;
        int n = flat >> 4, ks = flat & 15;
        uint4 v = *(const uint4*)(p + ((n * 256 + ks * 16) ^ ((n & 7) << 4)));
        *(uint4*)(Yo + (size_t)n * 128 + ks * 8) = v;
    }
}

// ============================================================
// FUSED GDFN tail: dw3x3+GELU gate (in-block, from hdn) + g2 GEMM (K=256)
// + bf16 residual -> fp32 out. Block = one image row x 128 cout.
// Gate tile lives in LDS (Gs[256][130], conflict-free gathers: 8-row step
// = 520 words = 8 mod 32 banks); epilogue staging aliases Gs.
// ============================================================
__global__ __launch_bounds__(256)
void gdfn2_kernel(const unsigned short* __restrict__ W,    // g2_w (128,256) bf16
                  const unsigned short* __restrict__ hdn,  // big (nb,512,NP) bf16
                  const unsigned short* __restrict__ w9,   // gd_w (512*9) bf16
                  float* __restrict__ Out,
                  const unsigned short* __restrict__ Res)  // xmid bf16
{
    __shared__ unsigned short Gs[256 * 130];   // 66.5 KB
    float* Stf = (float*)Gs;                   // epilogue alias (16.9 KB)
    const int tid = threadIdx.x;
    const int b = blockIdx.y;
    const int y = blockIdx.x;                  // image row
    const int n0 = y * 128;

    // ---- phase 0: gate = GELU(dw(x1)) * dw(x2) -> Gs (16 passes x 16 ch) ----
    {
        const int xi = (tid & 15) * 8;
        const int crow = tid >> 4;             // 0..15
        #pragma unroll
        for (int p = 0; p < 16; ++p) {
            int c = p * 16 + crow;             // 0..255
            const unsigned short* b1 = hdn + ((size_t)b * 512 + c) * NP + n0 + xi;
            const unsigned short* b2 = b1 + (size_t)256 * NP;
            float w1[9], w2[9];
            #pragma unroll
            for (int i = 0; i < 9; ++i) {
                w1[i] = b2f(w9[c * 9 + i]);
                w2[i] = b2f(w9[(c + 256) * 9 + i]);
            }
            float a1[8], a2[8];
            dw8(b1, y, xi, w1, a1);
            dw8(b2, y, xi, w2, a2);
            union { uint4 v; unsigned int d[4]; unsigned short u[8]; } res;
            #pragma unroll
            for (int j = 0; j < 8; ++j) {
                float u = a1[j];
                float tt = u * (0.7978845608f + 0.0356774081f * u * u);
                float e = __expf(2.f * tt);
                float th = 1.f - 2.f / (e + 1.f);
                float ge = 0.5f * u * (1.f + th);
                res.u[j] = f2b(ge * a2[j]);
            }
            unsigned int* d = (unsigned int*)&Gs[c * 130 + xi];   // 4B-aligned
            d[0] = res.d[0]; d[1] = res.d[1]; d[2] = res.d[2]; d[3] = res.d[3];
        }
    }
    __syncthreads();

    // ---- GEMM K=256, no k-loop staging/barriers ----
    const int lane = tid & 63, wid = tid >> 6;
    const int ln16 = lane & 15, quad = lane >> 4;
    const int wy = wid >> 1, wx = wid & 1;

    f32x4 acc[4][4];
    #pragma unroll
    for (int i = 0; i < 4; ++i)
        #pragma unroll
        for (int j = 0; j < 4; ++j) acc[i][j] = f32x4{0.f, 0.f, 0.f, 0.f};

    #pragma unroll
    for (int k0 = 0; k0 < 256; k0 += 32) {
        bf16x8 afr[4], bfr[4];
        #pragma unroll
        for (int mt = 0; mt < 4; ++mt) {
            int m = wy * 64 + mt * 16 + ln16;
            uint4 v = *(const uint4*)(W + (size_t)m * 256 + k0 + quad * 8);
            afr[mt] = *(bf16x8*)&v;
        }
        #pragma unroll
        for (int nt = 0; nt < 4; ++nt) {
            int n = wx * 64 + nt * 16 + ln16;
            union { bf16x8 v; unsigned short u[8]; } tmp;
            #pragma unroll
            for (int j = 0; j < 8; ++j) tmp.u[j] = Gs[(k0 + quad * 8 + j) * 130 + n];
            bfr[nt] = tmp.v;
        }
        #pragma unroll
        for (int mt = 0; mt < 4; ++mt)
            #pragma unroll
            for (int nt = 0; nt < 4; ++nt)
                acc[mt][nt] = __builtin_amdgcn_mfma_f32_16x16x32_bf16(
                    afr[mt], bfr[nt], acc[mt][nt], 0, 0, 0);
    }
    __syncthreads();   // all Gs reads done before aliasing as Stf

    // ---- epilogue: 4 passes of 32 co-rows; transpose -> vector res+store ----
    size_t outbase = (size_t)b * 128 * NP;
    #pragma unroll
    for (int mt = 0; mt < 4; ++mt) {
        int lr = wy * 16 + quad * 4;            // local row base 0..31
        #pragma unroll
        for (int nt = 0; nt < 4; ++nt) {
            int nn = wx * 64 + nt * 16 + ln16;
            #pragma unroll
            for (int r = 0; r < 4; ++r)
                Stf[(lr + r) * 132 + nn] = acc[mt][nt][r];
        }
        __syncthreads();
        #pragma unroll
        for (int i = 0; i < 4; ++i) {
            int flat = tid + i * 256;           // 0..1023
            int row = flat >> 5;                // 0..31
            int g = flat & 31;                  // 4-px group
            f32x4 v = *(const f32x4*)(&Stf[row * 132 + g * 4]);
            int absrow = (row >> 4) * 64 + mt * 16 + (row & 15);
            size_t idx = outbase + (size_t)absrow * NP + n0 + g * 4;
            union { uint2 u2; unsigned short u[4]; } rv;
            rv.u2 = *(const uint2*)(Res + idx);
            f32x4 o;
            #pragma unroll
            for (int k = 0; k < 4; ++k) o[k] = b2f(rv.u[k]) + v[k];
            *(f32x4*)(Out + idx) = o;
        }
        __syncthreads();
    }
}

// ---------- pipeline ----------
struct Bufs {
    unsigned short* xmid;   // nb*C*NP bf16 (trunk after MDTA, channel-major)
    unsigned short* y2;     // nb*NP*C bf16 PIXEL-MAJOR (LN2 out)
    unsigned short* big;    // nb*512*NP bf16 channel-major (qkv1 / hdn)
    float* Spart;           // nb*NH*32*256
    float* Npart;           // nb*NH*32*32
    unsigned short* W2;     // nb*128*128 bf16 (proj x blockdiag(P))
};

static void run_pipeline(const float* x_f32, float* out_f32,
                         const unsigned short* w,
                         const float* Saux, const float* Kaux,
                         const Bufs& B, int nb, hipStream_t stream)
{
    const unsigned short* temp    = w + 256;
    const unsigned short* qkv_p_w = w + 272;     // pre-scaled by ln1 gamma
    const unsigned short* qkv_d_w = w + 49424;
    const unsigned short* proj_w  = w + 52880;
    const unsigned short* ln2_w   = w + 69264;
    const unsigned short* ln2_b   = w + 69392;
    const unsigned short* g1_w    = w + 69520;
    const unsigned short* gd_w    = w + 135056;
    const unsigned short* g2_w    = w + 139664;

    // ---- MDTA ----
    lngemm_fused<<<dim3(NP / 64, nb), 256, 0, stream>>>(x_f32, qkv_p_w, Saux, Kaux, B.big);
    dwqkgram_kernel<<<dim3(NH, nb, 32), 256, 0, stream>>>(B.big, qkv_d_w, B.Spart, B.Npart);
    softwp_kernel<<<nb * NH, 256, 0, stream>>>(B.Spart, B.Npart, temp, proj_w, B.W2);
    projln_kernel<<<dim3(NP / 128, nb), 256, 0, stream>>>(B.W2, B.big, qkv_d_w, x_f32,
                                                          B.xmid, ln2_w, ln2_b, B.y2);

    // ---- GDFN ----
    gemm_bf16t_kernel<512><<<dim3(NP / 128, nb), 256, 0, stream>>>(g1_w, B.y2, B.big);
    gdfn2_kernel<<<dim3(128, nb), 256, 0, stream>>>(g2_w, B.big, gd_w, out_f32, B.xmid);
}

extern "C" void kernel_launch(void* const* d_in, const int* in_sizes, int n_in,
                              void* d_out, int out_size, void* d_ws, size_t ws_size,
                              hipStream_t stream)
{
    (void)in_sizes; (void)n_in; (void)out_size;
    const float* x = (const float*)d_in[0];
    char* ws = (char*)d_ws;

    size_t off = 0;
    unsigned short* wpack = (unsigned short*)(ws + off);
    off += (size_t)kWTotal * 2;
    off = (off + 255) & ~(size_t)255;
    float* Saux = (float*)(ws + off);  off += 384 * 4;
    float* Kaux = (float*)(ws + off);  off += 384 * 4;
    off = (off + 255) & ~(size_t)255;
    size_t header = off;

    auto layout = [&](int nb, size_t o, Bufs& B) -> size_t {
        B.xmid = (unsigned short*)(ws + o);  o += (size_t)nb * C * NP * 2;
        B.y2   = (unsigned short*)(ws + o);  o += (size_t)nb * C * NP * 2;
        B.big  = (unsigned short*)(ws + o);  o += (size_t)nb * 512 * NP * 2;
        B.Spart = (float*)(ws + o);          o += (size_t)nb * NH * 32 * 256 * 4;
        B.Npart = (float*)(ws + o);          o += (size_t)nb * NH * 32 * 32 * 4;
        B.W2   = (unsigned short*)(ws + o);  o += (size_t)nb * 128 * 128 * 2;
        return o;
    };

    Ptr11 P;
    for (int i = 0; i < 11; ++i) P.p[i] = (const float*)d_in[i + 1];
    cvt_w_kernel<<<dim3(256, 11), 256, 0, stream>>>(P, wpack);
    prep_lnw_kernel<<<3, 128, 0, stream>>>((const float*)d_in[4], (const float*)d_in[1],
                                           (const float*)d_in[2], Saux, Kaux);

    Bufs Bfull;
    size_t need_full = layout(4, header, Bfull);

    if (ws_size >= need_full) {
        run_pipeline(x, (float*)d_out, wpack, Saux, Kaux, Bfull, 4, stream);
    } else {
        Bufs B1;
        layout(1, header, B1);
        for (int b = 0; b < 4; ++b) {
            run_pipeline(x + (size_t)b * C * NP,
                         (float*)d_out + (size_t)b * C * NP,
                         wpack, Saux, Kaux, B1, 1, stream);
        }
    }
}

// Round 11
// 249.287 us; speedup vs baseline: 1.0440x; 1.0440x over previous
//
#include <hip/hip_runtime.h>
#include <cstdint>
#include <cstddef>

// ---------- types / helpers ----------
typedef float f32x4 __attribute__((ext_vector_type(4)));
typedef __bf16 bf16x8 __attribute__((ext_vector_type(8)));

__device__ __forceinline__ float b2f(unsigned short u) {
    union { unsigned int i; float f; } z; z.i = ((unsigned int)u) << 16; return z.f;
}
__device__ __forceinline__ unsigned short f2b(float f) {
    union { float f; unsigned int i; } z; z.f = f;
    unsigned int x = z.i;
    return (unsigned short)((x + 0x7FFFu + ((x >> 16) & 1u)) >> 16);
}

static constexpr int C = 128;
static constexpr int NP = 16384;      // H*W
static constexpr int NH = 8;

// ---------- weight pack: fp32 -> bf16 ----------
struct Ptr11 { const float* p[11]; };
__constant__ int kWN[11]   = {128, 128, 8, 49152, 3456, 16384, 128, 128, 65536, 4608, 32768};
__constant__ int kWOff[11] = {0, 128, 256, 272, 49424, 52880, 69264, 69392, 69520, 135056, 139664};
static constexpr int kWTotal = 172432;

__global__ __launch_bounds__(256)
void cvt_w_kernel(Ptr11 P, unsigned short* __restrict__ dst)
{
    int seg = blockIdx.y;
    int n = kWN[seg];
    int i = blockIdx.x * 256 + threadIdx.x;
    if (i >= n) return;
    dst[kWOff[seg] + i] = f2b(P.p[seg][i]);
}

// ---------- shared dwconv3 row helper: 8 px, halos via width-16 shuffles ----------
__device__ __forceinline__ void dw8(const unsigned short* base, int y, int xi,
                                    const float* wr, float* o)
{
    uint4 rv0 = uint4{0,0,0,0}, rv1, rv2 = uint4{0,0,0,0};
    if (y > 0)   rv0 = *(const uint4*)(base - 128);
    rv1 = *(const uint4*)(base);
    if (y < 127) rv2 = *(const uint4*)(base + 128);
    uint4 rows[3] = {rv0, rv1, rv2};
    #pragma unroll
    for (int j = 0; j < 8; ++j) o[j] = 0.f;
    #pragma unroll
    for (int r = 0; r < 3; ++r) {
        union { uint4 v; unsigned short u[8]; } cv; cv.v = rows[r];
        int lh = __shfl_up((int)cv.u[7], 1, 16);
        int rh = __shfl_down((int)cv.u[0], 1, 16);
        float p[10];
        p[0] = (xi > 0)   ? b2f((unsigned short)lh) : 0.f;
        p[9] = (xi < 120) ? b2f((unsigned short)rh) : 0.f;
        #pragma unroll
        for (int j = 0; j < 8; ++j) p[j + 1] = b2f(cv.u[j]);
        #pragma unroll
        for (int j = 0; j < 8; ++j)
            o[j] += wr[r * 3] * p[j] + wr[r * 3 + 1] * p[j + 1] + wr[r * 3 + 2] * p[j + 2];
    }
}

// ============================================================
// Scalar-store transposed+swizzled GEMM core (R5-verified) — lngemm only.
// ============================================================
template <int COUT>
__device__ __forceinline__ void gemm_core_tr_sc(
    const unsigned short* BsT,
    const unsigned short* __restrict__ W,     // (COUT, 128) bf16, row-major
    unsigned short* __restrict__ OutB,        // already + b*COUT*NP, channel-major
    int n0, int tid)
{
    const int lane = tid & 63;
    const int wid  = tid >> 6;
    const int ln16 = lane & 15, quad = lane >> 4;
    const int wy = wid >> 1, wx = wid & 1;
    const char* bs = (const char*)BsT;
    const int swz = (ln16 & 7) << 4;
    int rbase[4];
    #pragma unroll
    for (int nt = 0; nt < 4; ++nt) {
        int n = wx * 64 + nt * 16 + ln16;
        rbase[nt] = n * 256 + quad * 16;
    }

    for (int cc = 0; cc < COUT / 128; ++cc) {
        const int m0 = cc * 128;
        f32x4 acc[4][4];
        #pragma unroll
        for (int i = 0; i < 4; ++i)
            #pragma unroll
            for (int j = 0; j < 4; ++j) acc[i][j] = f32x4{0.f, 0.f, 0.f, 0.f};

        #pragma unroll
        for (int k0 = 0; k0 < 128; k0 += 32) {
            bf16x8 afr[4], bfr[4];
            #pragma unroll
            for (int mt = 0; mt < 4; ++mt) {
                int m = m0 + wy * 64 + mt * 16 + ln16;
                uint4 v = *(const uint4*)(W + (size_t)m * 128 + k0 + quad * 8);
                afr[mt] = *(bf16x8*)&v;
            }
            #pragma unroll
            for (int nt = 0; nt < 4; ++nt) {
                uint4 v = *(const uint4*)(bs + ((rbase[nt] + k0 * 2) ^ swz));
                bfr[nt] = *(bf16x8*)&v;
            }
            #pragma unroll
            for (int mt = 0; mt < 4; ++mt)
                #pragma unroll
                for (int nt = 0; nt < 4; ++nt)
                    acc[mt][nt] = __builtin_amdgcn_mfma_f32_16x16x32_bf16(
                        afr[mt], bfr[nt], acc[mt][nt], 0, 0, 0);
        }
        #pragma unroll
        for (int mt = 0; mt < 4; ++mt)
            #pragma unroll
            for (int nt = 0; nt < 4; ++nt) {
                int co0 = m0 + wy * 64 + mt * 16 + quad * 4;
                int n = n0 + wx * 64 + nt * 16 + ln16;
                #pragma unroll
                for (int r = 0; r < 4; ++r)
                    OutB[(size_t)(co0 + r) * NP + n] = f2b(acc[mt][nt][r]);
            }
    }
}

// ============================================================
// Vector-store transposed+swizzled GEMM core (R9-verified) — g1.
// St: 64 co x 128 px staging, row 272B (17x16B).
// ============================================================
template <int COUT>
__device__ __forceinline__ void gemm_core_tr_v(
    const unsigned short* BsT,
    unsigned short* St,                        // [64*136]
    const unsigned short* __restrict__ W,      // (COUT, 128) bf16, row-major
    unsigned short* __restrict__ OutB,         // already + b*COUT*NP
    int n0, int tid)
{
    const int lane = tid & 63;
    const int wid  = tid >> 6;
    const int ln16 = lane & 15, quad = lane >> 4;
    const int wy = wid >> 1, wx = wid & 1;
    const char* bs = (const char*)BsT;
    const int swz = (ln16 & 7) << 4;
    int rbase[4];
    #pragma unroll
    for (int nt = 0; nt < 4; ++nt) {
        int n = wx * 64 + nt * 16 + ln16;
        rbase[nt] = n * 256 + quad * 16;
    }

    for (int cc = 0; cc < COUT / 128; ++cc) {
        const int m0 = cc * 128;
        f32x4 acc[4][4];
        #pragma unroll
        for (int i = 0; i < 4; ++i)
            #pragma unroll
            for (int j = 0; j < 4; ++j) acc[i][j] = f32x4{0.f, 0.f, 0.f, 0.f};

        #pragma unroll
        for (int k0 = 0; k0 < 128; k0 += 32) {
            bf16x8 afr[4], bfr[4];
            #pragma unroll
            for (int mt = 0; mt < 4; ++mt) {
                int m = m0 + wy * 64 + mt * 16 + ln16;
                uint4 v = *(const uint4*)(W + (size_t)m * 128 + k0 + quad * 8);
                afr[mt] = *(bf16x8*)&v;
            }
            #pragma unroll
            for (int nt = 0; nt < 4; ++nt) {
                uint4 v = *(const uint4*)(bs + ((rbase[nt] + k0 * 2) ^ swz));
                bfr[nt] = *(bf16x8*)&v;
            }
            #pragma unroll
            for (int mt = 0; mt < 4; ++mt)
                #pragma unroll
                for (int nt = 0; nt < 4; ++nt)
                    acc[mt][nt] = __builtin_amdgcn_mfma_f32_16x16x32_bf16(
                        afr[mt], bfr[nt], acc[mt][nt], 0, 0, 0);
        }
        #pragma unroll
        for (int h = 0; h < 2; ++h) {
            if (wy == h) {
                #pragma unroll
                for (int mt = 0; mt < 4; ++mt) {
                    int lr0 = mt * 16 + quad * 4;
                    #pragma unroll
                    for (int nt = 0; nt < 4; ++nt) {
                        int nn = wx * 64 + nt * 16 + ln16;
                        #pragma unroll
                        for (int r = 0; r < 4; ++r)
                            St[(lr0 + r) * 136 + nn] = f2b(acc[mt][nt][r]);
                    }
                }
            }
            __syncthreads();
            #pragma unroll
            for (int i = 0; i < 4; ++i) {
                int flat = tid + i * 256;    // 0..1023
                int row = flat >> 4;         // 0..63
                int g = flat & 15;           // 8-px group (128 px)
                uint4 v = *(const uint4*)(&St[row * 136 + g * 8]);
                *(uint4*)(&OutB[(size_t)(m0 + h * 64 + row) * NP + n0 + g * 8]) = v;
            }
            __syncthreads();
        }
    }
}

// ---------- fused LN(channel) + 1x1-conv GEMM (R5 monolith, untouched) ----------
template <int COUT>
__global__ __launch_bounds__(256)
void lngemm_kernel(const float* __restrict__ x,              // (nb, C, NP) fp32
                   const unsigned short* __restrict__ lg,
                   const unsigned short* __restrict__ lb,
                   const unsigned short* __restrict__ W,     // (COUT, 128) bf16
                   unsigned short* __restrict__ Out)         // (nb, COUT, NP) bf16
{
    __shared__ unsigned short BsT[128 * 128];
    __shared__ float Ssum[8][128], Ssq[8][128], Mu[128], Rs[128];
    const int tid = threadIdx.x;
    const int b = blockIdx.y;
    const int n0 = blockIdx.x * 128;
    const int pxg = tid & 31;       // 4 consecutive pixels
    const int cseg = tid >> 5;      // 16 channels
    const float* xb = x + (size_t)b * C * NP + n0 + pxg * 4;

    f32x4 hv[16];
    f32x4 vs = f32x4{0.f, 0.f, 0.f, 0.f}, vq = f32x4{0.f, 0.f, 0.f, 0.f};
    #pragma unroll
    for (int i = 0; i < 16; ++i) {
        f32x4 v = *(const f32x4*)(xb + (size_t)(cseg * 16 + i) * NP);
        hv[i] = v; vs += v; vq += v * v;
    }
    #pragma unroll
    for (int j = 0; j < 4; ++j) {
        Ssum[cseg][pxg * 4 + j] = vs[j];
        Ssq[cseg][pxg * 4 + j]  = vq[j];
    }
    __syncthreads();
    if (tid < 128) {
        float s = 0.f, q = 0.f;
        #pragma unroll
        for (int e = 0; e < 8; ++e) { s += Ssum[e][tid]; q += Ssq[e][tid]; }
        float mu = s * (1.f / 128.f);
        float var = q * (1.f / 128.f) - mu * mu;
        Mu[tid] = mu;
        Rs[tid] = rsqrtf(fmaxf(var, 0.f) + 1e-5f);
    }
    __syncthreads();
    f32x4 mu4 = *(const f32x4*)(&Mu[pxg * 4]);
    f32x4 rs4 = *(const f32x4*)(&Rs[pxg * 4]);

    float gwv[16], bwv[16];
    #pragma unroll
    for (int i = 0; i < 16; ++i) {
        gwv[i] = b2f(lg[cseg * 16 + i]);
        bwv[i] = b2f(lb[cseg * 16 + i]);
    }

    char* p = (char*)BsT;
    #pragma unroll
    for (int j = 0; j < 4; ++j) {
        int n = pxg * 4 + j;
        union { uint4 v[2]; unsigned short u[16]; } o;
        #pragma unroll
        for (int i = 0; i < 16; ++i)
            o.u[i] = f2b((hv[i][j] - mu4[j]) * rs4[j] * gwv[i] + bwv[i]);
        int base = n * 256 + cseg * 32;
        int sw = (n & 7) << 4;
        *(uint4*)(p + (base ^ sw))        = o.v[0];
        *(uint4*)(p + ((base + 16) ^ sw)) = o.v[1];
    }
    __syncthreads();
    gemm_core_tr_sc<COUT>(BsT, W, Out + (size_t)b * COUT * NP, n0, tid);
}

// ---------- plain GEMM from PIXEL-MAJOR bf16 input (g1), vector epilogue ----------
template <int COUT>
__global__ __launch_bounds__(256)
void gemm_bf16t_kernel(const unsigned short* __restrict__ W,   // (COUT,128) bf16
                       const unsigned short* __restrict__ Xt,  // (nb, NP, 128) bf16
                       unsigned short* __restrict__ Out)       // (nb, COUT, NP) bf16
{
    __shared__ unsigned short BsT[128 * 128];
    __shared__ unsigned short St[64 * 136];
    const int tid = threadIdx.x;
    const int b = blockIdx.y;
    const int n0 = blockIdx.x * 128;
    const unsigned short* Xb = Xt + (size_t)b * NP * 128 + (size_t)n0 * 128;
    char* p = (char*)BsT;
    #pragma unroll
    for (int r = 0; r < 8; ++r) {
        int flat = tid + r * 256;
        int n = flat >> 4, ks = flat & 15;
        uint4 v = *(const uint4*)(Xb + (size_t)n * 128 + ks * 8);
        *(uint4*)(p + ((n * 256 + ks * 16) ^ ((n & 7) << 4))) = v;
    }
    __syncthreads();
    gemm_core_tr_v<COUT>(BsT, St, W, Out + (size_t)b * COUT * NP, n0, tid);
}

// ---------- FUSED dwconv3(q,k) + Gram partial + sumsq partial ----------
__global__ __launch_bounds__(256)
void dwqkgram_kernel(const unsigned short* __restrict__ big,   // (nb,384,NP)
                     const unsigned short* __restrict__ w9,    // qkv_d_w (384*9)
                     float* __restrict__ Spart,                // [bh][32][256]
                     float* __restrict__ Npart)                // [bh][32][32]
{
    __shared__ unsigned short qs_[16 * 520];
    __shared__ unsigned short ks_[16 * 520];
    __shared__ float Sred[4][256];
    const int h = blockIdx.x, b = blockIdx.y, sp = blockIdx.z;
    const int tid = threadIdx.x;
    const int wid = tid >> 6, lane = tid & 63;
    const int xi = (tid & 15) * 8;
    const int yr = (tid >> 4) & 3;       // row within slab
    const int y  = sp * 4 + yr;          // image row
    const int bh = b * NH + h;
    float* Np = Npart + ((size_t)bh * 32 + sp) * 32;

    #pragma unroll
    for (int p = 0; p < 4; ++p) {
        int qc = p * 4 + wid;            // local channel 0..15, one per wave
        #pragma unroll
        for (int s = 0; s < 2; ++s) {    // 0 = q, 1 = k
            int ch = s * 128 + h * 16 + qc;
            const unsigned short* base = big + ((size_t)b * 384 + ch) * NP + y * 128 + xi;
            float wr[9];
            #pragma unroll
            for (int i = 0; i < 9; ++i) wr[i] = b2f(w9[ch * 9 + i]);
            float o[8];
            dw8(base, y, xi, wr, o);
            union { uint4 v; unsigned short u[8]; } res;
            float ss = 0.f;
            #pragma unroll
            for (int j = 0; j < 8; ++j) {
                res.u[j] = f2b(o[j]);
                float vv = b2f(res.u[j]);
                ss += vv * vv;
            }
            unsigned short* tile = s ? ks_ : qs_;
            *(uint4*)(&tile[qc * 520 + yr * 128 + xi]) = res.v;
            #pragma unroll
            for (int od = 32; od > 0; od >>= 1) ss += __shfl_xor(ss, od, 64);
            if (lane == 0) Np[s * 16 + qc] = ss;
        }
    }
    __syncthreads();

    const int ln16 = lane & 15, quad = lane >> 4;
    f32x4 acc = f32x4{0.f, 0.f, 0.f, 0.f};
    #pragma unroll
    for (int i = 0; i < 4; ++i) {
        int off = wid * 128 + i * 32 + quad * 8;
        uint4 qv = *(const uint4*)(&qs_[ln16 * 520 + off]);
        uint4 kv = *(const uint4*)(&ks_[ln16 * 520 + off]);
        acc = __builtin_amdgcn_mfma_f32_16x16x32_bf16(*(bf16x8*)&qv, *(bf16x8*)&kv, acc, 0, 0, 0);
    }
    #pragma unroll
    for (int r = 0; r < 4; ++r) Sred[wid][(quad * 4 + r) * 16 + ln16] = acc[r];
    __syncthreads();
    float ssum = Sred[0][tid] + Sred[1][tid] + Sred[2][tid] + Sred[3][tid];
    Spart[((size_t)bh * 32 + sp) * 256 + tid] = ssum;
}

// ---------- softmax + fused W' = proj x blockdiag(P) ----------
__global__ __launch_bounds__(256)
void softwp_kernel(const float* __restrict__ Spart, const float* __restrict__ Npart,
                   const unsigned short* __restrict__ temp,
                   const unsigned short* __restrict__ proj,   // (128,128) bf16
                   unsigned short* __restrict__ W2)           // (nb,128,128) bf16
{
    __shared__ float Ps[256];
    int bh = blockIdx.x;
    int b = bh >> 3, h = bh & 7;
    int t = threadIdx.x;            // 256 = 16x16
    int dq = t >> 4, dk = t & 15;
    float sacc = 0.f;
    const float* Sp = Spart + (size_t)bh * 32 * 256;
    #pragma unroll
    for (int j = 0; j < 32; ++j) sacc += Sp[j * 256 + t];
    const float* Np = Npart + (size_t)bh * 32 * 32;
    float sq = 0.f, sk = 0.f;
    #pragma unroll
    for (int sp = 0; sp < 32; ++sp) { sq += Np[sp * 32 + dq]; sk += Np[sp * 32 + 16 + dk]; }
    float nq = fmaxf(sqrtf(sq), 1e-12f);
    float nk = fmaxf(sqrtf(sk), 1e-12f);
    float v = sacc / (nq * nk) * b2f(temp[h]);
    float m = v;
    #pragma unroll
    for (int o = 8; o > 0; o >>= 1) m = fmaxf(m, __shfl_xor(m, o, 16));
    float e = __expf(v - m);
    float s = e;
    #pragma unroll
    for (int o = 8; o > 0; o >>= 1) s += __shfl_xor(s, o, 16);
    Ps[t] = e / s;                 // P[dq][dk]
    __syncthreads();

    int co = t >> 1;
    int eo = (t & 1) * 8;
    union { uint4 v[2]; unsigned short u[16]; } pw;
    pw.v[0] = *(const uint4*)(proj + (size_t)co * 128 + h * 16);
    pw.v[1] = *(const uint4*)(proj + (size_t)co * 128 + h * 16 + 8);
    float prw[16];
    #pragma unroll
    for (int d = 0; d < 16; ++d) prw[d] = b2f(pw.u[d]);
    union { uint4 v; unsigned short u[8]; } o8;
    #pragma unroll
    for (int j = 0; j < 8; ++j) {
        int ee = eo + j;
        float s2 = 0.f;
        #pragma unroll
        for (int d = 0; d < 16; ++d) s2 += prw[d] * Ps[d * 16 + ee];
        o8.u[j] = f2b(s2);
    }
    *(uint4*)(W2 + ((size_t)b * 128 + co) * 128 + h * 16 + eo) = o8.v;
}

// ---------- proj' GEMM (W2[b] x dw-v computed IN-BLOCK) + residual + LN2 ----------
__global__ __launch_bounds__(256)
void projln_kernel(const unsigned short* __restrict__ W2,    // (nb,128,128) bf16
                   const unsigned short* __restrict__ big,   // (nb,384,NP) bf16
                   const unsigned short* __restrict__ w9,    // qkv_d_w
                   const float* __restrict__ Res,            // x fp32 (nb,128,NP)
                   unsigned short* __restrict__ Xmid,        // bf16 trunk out
                   const unsigned short* __restrict__ lg,
                   const unsigned short* __restrict__ lb,
                   unsigned short* __restrict__ Y2t)         // (nb, NP, 128) bf16
{
    __shared__ unsigned short Bs[128][130];
    __shared__ float RedS[2][128], RedQ[2][128], Mu[128], Rs[128];
    const int tid = threadIdx.x;
    const int b = blockIdx.y;
    const int y = blockIdx.x;            // image row
    const int n0 = y * 128;
    const unsigned short* Wb = W2 + (size_t)b * 16384;

    // ---- phase 0: dw-conv v -> Bs (8 passes x 16 channels) ----
    {
        const int xi = (tid & 15) * 8;
        const int crow = tid >> 4;       // 0..15
        #pragma unroll
        for (int p = 0; p < 8; ++p) {
            int c = p * 16 + crow;
            int ch = 256 + c;
            const unsigned short* base = big + ((size_t)b * 384 + ch) * NP + n0 + xi;
            float wr[9];
            #pragma unroll
            for (int i = 0; i < 9; ++i) wr[i] = b2f(w9[ch * 9 + i]);
            float o[8];
            dw8(base, y, xi, wr, o);
            union { uint4 v; unsigned int d[4]; unsigned short u[8]; } res;
            #pragma unroll
            for (int j = 0; j < 8; ++j) res.u[j] = f2b(o[j]);
            unsigned int* d = (unsigned int*)&Bs[c][xi];   // 4B-aligned (260B rows)
            d[0] = res.d[0]; d[1] = res.d[1]; d[2] = res.d[2]; d[3] = res.d[3];
        }
    }
    __syncthreads();

    const int lane = tid & 63, wid = tid >> 6;
    const int ln16 = lane & 15, quad = lane >> 4;
    const int wy = wid >> 1, wx = wid & 1;

    f32x4 acc[4][4];
    #pragma unroll
    for (int i = 0; i < 4; ++i)
        #pragma unroll
        for (int j = 0; j < 4; ++j) acc[i][j] = f32x4{0.f, 0.f, 0.f, 0.f};

    #pragma unroll
    for (int k0 = 0; k0 < 128; k0 += 32) {
        bf16x8 afr[4], bfr[4];
        #pragma unroll
        for (int mt = 0; mt < 4; ++mt) {
            int m = wy * 64 + mt * 16 + ln16;
            uint4 v = *(const uint4*)(Wb + (size_t)m * 128 + k0 + quad * 8);
            afr[mt] = *(bf16x8*)&v;
        }
        #pragma unroll
        for (int nt = 0; nt < 4; ++nt) {
            int n = wx * 64 + nt * 16 + ln16;
            union { bf16x8 v; unsigned short u[8]; } tmp;
            #pragma unroll
            for (int j = 0; j < 8; ++j) tmp.u[j] = Bs[k0 + quad * 8 + j][n];
            bfr[nt] = tmp.v;
        }
        #pragma unroll
        for (int mt = 0; mt < 4; ++mt)
            #pragma unroll
            for (int nt = 0; nt < 4; ++nt)
                acc[mt][nt] = __builtin_amdgcn_mfma_f32_16x16x32_bf16(
                    afr[mt], bfr[nt], acc[mt][nt], 0, 0, 0);
    }

    // pass A: trunk = Res + acc -> Xmid (bf16, channel-major), per-pixel partials
    size_t base = (size_t)b * 128 * NP;
    float ps[4] = {0.f, 0.f, 0.f, 0.f}, pq[4] = {0.f, 0.f, 0.f, 0.f};
    #pragma unroll
    for (int mt = 0; mt < 4; ++mt)
        #pragma unroll
        for (int nt = 0; nt < 4; ++nt) {
            int co0 = wy * 64 + mt * 16 + quad * 4;
            int n = n0 + wx * 64 + nt * 16 + ln16;
            #pragma unroll
            for (int r = 0; r < 4; ++r) {
                size_t idx = base + (size_t)(co0 + r) * NP + n;
                float tv = Res[idx] + acc[mt][nt][r];
                Xmid[idx] = f2b(tv);
                acc[mt][nt][r] = tv;
                ps[nt] += tv; pq[nt] += tv * tv;
            }
        }
    #pragma unroll
    for (int nt = 0; nt < 4; ++nt) {
        ps[nt] += __shfl_xor(ps[nt], 16, 64); ps[nt] += __shfl_xor(ps[nt], 32, 64);
        pq[nt] += __shfl_xor(pq[nt], 16, 64); pq[nt] += __shfl_xor(pq[nt], 32, 64);
    }
    if (quad == 0) {
        #pragma unroll
        for (int nt = 0; nt < 4; ++nt) {
            int nn = wx * 64 + nt * 16 + ln16;
            RedS[wy][nn] = ps[nt]; RedQ[wy][nn] = pq[nt];
        }
    }
    __syncthreads();
    if (tid < 128) {
        float s = RedS[0][tid] + RedS[1][tid];
        float q = RedQ[0][tid] + RedQ[1][tid];
        float mu = s * (1.f / 128.f);
        float var = q * (1.f / 128.f) - mu * mu;
        Mu[tid] = mu; Rs[tid] = rsqrtf(fmaxf(var, 0.f) + 1e-5f);
    }
    __syncthreads();

    // pass B: y2 = LN2(trunk) -> swizzled flat reuse of Bs as [n][c] (256B rows)
    char* p = (char*)Bs;
    #pragma unroll
    for (int mt = 0; mt < 4; ++mt) {
        int co0 = wy * 64 + mt * 16 + quad * 4;
        union { uint2 v; unsigned short u[4]; } gv, bv;
        gv.v = *(const uint2*)(lg + co0);
        bv.v = *(const uint2*)(lb + co0);
        float gw[4], bw[4];
        #pragma unroll
        for (int r = 0; r < 4; ++r) { gw[r] = b2f(gv.u[r]); bw[r] = b2f(bv.u[r]); }
        #pragma unroll
        for (int nt = 0; nt < 4; ++nt) {
            int nn = wx * 64 + nt * 16 + ln16;
            float mu = Mu[nn], rs = Rs[nn];
            union { uint2 v; unsigned short u[4]; } t2;
            #pragma unroll
            for (int r = 0; r < 4; ++r)
                t2.u[r] = f2b((acc[mt][nt][r] - mu) * rs * gw[r] + bw[r]);
            int addr = (nn * 256 + co0 * 2) ^ ((nn & 7) << 4);
            *(uint2*)(p + addr) = t2.v;
        }
    }
    __syncthreads();

    unsigned short* Yo = Y2t + (size_t)b * NP * 128 + (size_t)n0 * 128;
    #pragma unroll
    for (int r = 0; r < 8; ++r) {
        int flat = tid + r * 256;
        int n = flat >> 4, ks = flat & 15;
        uint4 v = *(const uint4*)(p + ((n * 256 + ks * 16) ^ ((n & 7) << 4)));
        *(uint4*)(Yo + (size_t)n * 128 + ks * 8) = v;
    }
}

// ---------- g2 GEMM (K=256) + bf16 residual -> fp32 out, vectorized epilogue ----------
template <int K>
__global__ __launch_bounds__(256)
void gemm_pconv(const unsigned short* __restrict__ W,   // (Cout, K) bf16
                const unsigned short* __restrict__ X,   // (nb, K, NP) bf16
                float* __restrict__ Out,
                const unsigned short* __restrict__ Res, // bf16 trunk
                int Cout)
{
    __shared__ unsigned short Bs[32][130];
    __shared__ float Stf[32 * 132];               // 32 co x 128 px fp32
    const int tid = threadIdx.x;
    const int b = blockIdx.z;
    const int n0 = blockIdx.x * 128;
    const int m0 = blockIdx.y * 128;
    const unsigned short* Xb = X + (size_t)b * K * NP;
    const int wid = tid >> 6;
    const int lane = tid & 63;
    const int ln16 = lane & 15;
    const int quad = lane >> 4;
    const int wy = wid >> 1;
    const int wx = wid & 1;

    f32x4 acc[4][4];
    #pragma unroll
    for (int i = 0; i < 4; ++i)
        #pragma unroll
        for (int j = 0; j < 4; ++j)
            acc[i][j] = f32x4{0.f, 0.f, 0.f, 0.f};

    for (int k0 = 0; k0 < K; k0 += 32) {
        #pragma unroll
        for (int r = 0; r < 2; ++r) {
            int flat = tid + r * 256;
            int kk = flat >> 4;
            int nn = (flat & 15) * 8;
            uint4 v = *(const uint4*)(Xb + (size_t)(k0 + kk) * NP + n0 + nn);
            unsigned int* d = (unsigned int*)&Bs[kk][nn];
            d[0] = v.x; d[1] = v.y; d[2] = v.z; d[3] = v.w;
        }
        __syncthreads();

        bf16x8 afr[4];
        #pragma unroll
        for (int mt = 0; mt < 4; ++mt) {
            int m = m0 + wy * 64 + mt * 16 + ln16;
            uint4 v = *(const uint4*)(W + (size_t)m * K + k0 + quad * 8);
            afr[mt] = *(bf16x8*)&v;
        }
        bf16x8 bfr[4];
        #pragma unroll
        for (int nt = 0; nt < 4; ++nt) {
            int n = wx * 64 + nt * 16 + ln16;
            union { bf16x8 v; unsigned short u[8]; } tmp;
            #pragma unroll
            for (int j = 0; j < 8; ++j) tmp.u[j] = Bs[quad * 8 + j][n];
            bfr[nt] = tmp.v;
        }
        #pragma unroll
        for (int mt = 0; mt < 4; ++mt)
            #pragma unroll
            for (int nt = 0; nt < 4; ++nt)
                acc[mt][nt] = __builtin_amdgcn_mfma_f32_16x16x32_bf16(
                    afr[mt], bfr[nt], acc[mt][nt], 0, 0, 0);
        __syncthreads();
    }

    // epilogue: 4 passes of 32 co-rows; Stf transpose -> vector Res reads + f32x4 stores
    size_t outbase = (size_t)b * Cout * NP;
    #pragma unroll
    for (int mt = 0; mt < 4; ++mt) {
        int lr = wy * 16 + quad * 4;            // local row base 0..31
        #pragma unroll
        for (int nt = 0; nt < 4; ++nt) {
            int nn = wx * 64 + nt * 16 + ln16;
            #pragma unroll
            for (int r = 0; r < 4; ++r)
                Stf[(lr + r) * 132 + nn] = acc[mt][nt][r];
        }
        __syncthreads();
        #pragma unroll
        for (int i = 0; i < 4; ++i) {
            int flat = tid + i * 256;           // 0..1023
            int row = flat >> 5;                // 0..31
            int g = flat & 31;                  // 4-px group
            f32x4 v = *(const f32x4*)(&Stf[row * 132 + g * 4]);
            int absrow = m0 + (row >> 4) * 64 + mt * 16 + (row & 15);
            size_t idx = outbase + (size_t)absrow * NP + n0 + g * 4;
            union { uint2 u2; unsigned short u[4]; } rv;
            rv.u2 = *(const uint2*)(Res + idx);
            f32x4 o;
            #pragma unroll
            for (int k = 0; k < 4; ++k) o[k] = b2f(rv.u[k]) + v[k];
            *(f32x4*)(Out + idx) = o;
        }
        __syncthreads();
    }
}

// ---------- fused dw3x3 + fast-GELU gate ----------
__global__ __launch_bounds__(256)
void dwgelu_kernel(const unsigned short* __restrict__ hdn,
                   const unsigned short* __restrict__ w9,
                   unsigned short* __restrict__ g)
{
    int t = blockIdx.x * 256 + threadIdx.x;
    int xi = (t & 15) * 8;
    int y  = (t >> 4) & 127;
    int bc = t >> 11;
    int c  = bc & 255;
    int b  = bc >> 8;
    const unsigned short* base1 = hdn + ((size_t)b * 512 + c) * NP + y * 128 + xi;
    const unsigned short* base2 = base1 + (size_t)256 * NP;

    float w1[9], w2[9];
    #pragma unroll
    for (int i = 0; i < 9; ++i) {
        w1[i] = b2f(w9[c * 9 + i]);
        w2[i] = b2f(w9[(c + 256) * 9 + i]);
    }

    float a1[8], a2[8];
    dw8(base1, y, xi, w1, a1);
    dw8(base2, y, xi, w2, a2);

    union { uint4 v; unsigned short u[8]; } res;
    #pragma unroll
    for (int j = 0; j < 8; ++j) {
        float u = a1[j];
        float tt = u * (0.7978845608f + 0.0356774081f * u * u);
        float e = __expf(2.f * tt);
        float th = 1.f - 2.f / (e + 1.f);
        float ge = 0.5f * u * (1.f + th);
        res.u[j] = f2b(ge * a2[j]);
    }
    *(uint4*)(g + (size_t)bc * NP + y * 128 + xi) = res.v;
}

// ---------- pipeline ----------
struct Bufs {
    unsigned short* xmid;   // nb*C*NP bf16 (trunk after MDTA, channel-major)
    unsigned short* y2;     // nb*NP*C bf16 PIXEL-MAJOR (LN2 out)
    unsigned short* big;    // nb*512*NP bf16 channel-major (qkv1 / hdn)
    unsigned short* mid;    // nb*256*NP bf16 channel-major (gate out)
    float* Spart;           // nb*NH*32*256
    float* Npart;           // nb*NH*32*32
    unsigned short* W2;     // nb*128*128 bf16 (proj x blockdiag(P))
};

static void run_pipeline(const float* x_f32, float* out_f32,
                         const unsigned short* w,
                         const Bufs& B, int nb, hipStream_t stream)
{
    const unsigned short* ln1_w   = w + 0;
    const unsigned short* ln1_b   = w + 128;
    const unsigned short* temp    = w + 256;
    const unsigned short* qkv_p_w = w + 272;
    const unsigned short* qkv_d_w = w + 49424;
    const unsigned short* proj_w  = w + 52880;
    const unsigned short* ln2_w   = w + 69264;
    const unsigned short* ln2_b   = w + 69392;
    const unsigned short* g1_w    = w + 69520;
    const unsigned short* gd_w    = w + 135056;
    const unsigned short* g2_w    = w + 139664;

    // ---- MDTA ----
    lngemm_kernel<384><<<dim3(NP / 128, nb), 256, 0, stream>>>(x_f32, ln1_w, ln1_b, qkv_p_w, B.big);
    dwqkgram_kernel<<<dim3(NH, nb, 32), 256, 0, stream>>>(B.big, qkv_d_w, B.Spart, B.Npart);
    softwp_kernel<<<nb * NH, 256, 0, stream>>>(B.Spart, B.Npart, temp, proj_w, B.W2);
    projln_kernel<<<dim3(NP / 128, nb), 256, 0, stream>>>(B.W2, B.big, qkv_d_w, x_f32,
                                                          B.xmid, ln2_w, ln2_b, B.y2);

    // ---- GDFN ----
    gemm_bf16t_kernel<512><<<dim3(NP / 128, nb), 256, 0, stream>>>(g1_w, B.y2, B.big);
    dwgelu_kernel<<<nb * 256 * NP / 2048, 256, 0, stream>>>(B.big, gd_w, B.mid);
    gemm_pconv<256><<<dim3(NP / 128, 1, nb), 256, 0, stream>>>(g2_w, B.mid, out_f32, B.xmid, 128);
}

extern "C" void kernel_launch(void* const* d_in, const int* in_sizes, int n_in,
                              void* d_out, int out_size, void* d_ws, size_t ws_size,
                              hipStream_t stream)
{
    (void)in_sizes; (void)n_in; (void)out_size;
    const float* x = (const float*)d_in[0];
    char* ws = (char*)d_ws;

    size_t off = 0;
    unsigned short* wpack = (unsigned short*)(ws + off);
    off += (size_t)kWTotal * 2;
    off = (off + 255) & ~(size_t)255;
    size_t header = off;

    auto layout = [&](int nb, size_t o, Bufs& B) -> size_t {
        B.xmid = (unsigned short*)(ws + o);  o += (size_t)nb * C * NP * 2;
        B.y2   = (unsigned short*)(ws + o);  o += (size_t)nb * C * NP * 2;
        B.big  = (unsigned short*)(ws + o);  o += (size_t)nb * 512 * NP * 2;
        B.mid  = (unsigned short*)(ws + o);  o += (size_t)nb * 256 * NP * 2;
        B.Spart = (float*)(ws + o);          o += (size_t)nb * NH * 32 * 256 * 4;
        B.Npart = (float*)(ws + o);          o += (size_t)nb * NH * 32 * 32 * 4;
        B.W2   = (unsigned short*)(ws + o);  o += (size_t)nb * 128 * 128 * 2;
        return o;
    };

    Ptr11 P;
    for (int i = 0; i < 11; ++i) P.p[i] = (const float*)d_in[i + 1];
    cvt_w_kernel<<<dim3(256, 11), 256, 0, stream>>>(P, wpack);

    Bufs Bfull;
    size_t need_full = layout(4, header, Bfull);

    if (ws_size >= need_full) {
        run_pipeline(x, (float*)d_out, wpack, Bfull, 4, stream);
    } else {
        Bufs B1;
        layout(1, header, B1);
        for (int b = 0; b < 4; ++b) {
            run_pipeline(x + (size_t)b * C * NP,
                         (float*)d_out + (size_t)b * C * NP,
                         wpack, B1, 1, stream);
        }
    }
}

// Round 12
// 244.757 us; speedup vs baseline: 1.0633x; 1.0185x over previous
//
#include <hip/hip_runtime.h>
#include <cstdint>
#include <cstddef>

// ---------- types / helpers ----------
typedef float f32x4 __attribute__((ext_vector_type(4)));
typedef __bf16 bf16x8 __attribute__((ext_vector_type(8)));

__device__ __forceinline__ float b2f(unsigned short u) {
    union { unsigned int i; float f; } z; z.i = ((unsigned int)u) << 16; return z.f;
}
__device__ __forceinline__ unsigned short f2b(float f) {
    union { float f; unsigned int i; } z; z.f = f;
    unsigned int x = z.i;
    return (unsigned short)((x + 0x7FFFu + ((x >> 16) & 1u)) >> 16);
}

static constexpr int C = 128;
static constexpr int NP = 16384;      // H*W
static constexpr int NH = 8;

// ---------- weight pack: fp32 -> bf16 ----------
struct Ptr11 { const float* p[11]; };
__constant__ int kWN[11]   = {128, 128, 8, 49152, 3456, 16384, 128, 128, 65536, 4608, 32768};
__constant__ int kWOff[11] = {0, 128, 256, 272, 49424, 52880, 69264, 69392, 69520, 135056, 139664};
static constexpr int kWTotal = 172432;

__global__ __launch_bounds__(256)
void cvt_w_kernel(Ptr11 P, unsigned short* __restrict__ dst)
{
    int seg = blockIdx.y;
    int n = kWN[seg];
    int i = blockIdx.x * 256 + threadIdx.x;
    if (i >= n) return;
    dst[kWOff[seg] + i] = f2b(P.p[seg][i]);
}

// ---------- shared dwconv3 row helper: 8 px, halos via width-16 shuffles ----------
__device__ __forceinline__ void dw8(const unsigned short* base, int y, int xi,
                                    const float* wr, float* o)
{
    uint4 rv0 = uint4{0,0,0,0}, rv1, rv2 = uint4{0,0,0,0};
    if (y > 0)   rv0 = *(const uint4*)(base - 128);
    rv1 = *(const uint4*)(base);
    if (y < 127) rv2 = *(const uint4*)(base + 128);
    uint4 rows[3] = {rv0, rv1, rv2};
    #pragma unroll
    for (int j = 0; j < 8; ++j) o[j] = 0.f;
    #pragma unroll
    for (int r = 0; r < 3; ++r) {
        union { uint4 v; unsigned short u[8]; } cv; cv.v = rows[r];
        int lh = __shfl_up((int)cv.u[7], 1, 16);
        int rh = __shfl_down((int)cv.u[0], 1, 16);
        float p[10];
        p[0] = (xi > 0)   ? b2f((unsigned short)lh) : 0.f;
        p[9] = (xi < 120) ? b2f((unsigned short)rh) : 0.f;
        #pragma unroll
        for (int j = 0; j < 8; ++j) p[j + 1] = b2f(cv.u[j]);
        #pragma unroll
        for (int j = 0; j < 8; ++j)
            o[j] += wr[r * 3] * p[j] + wr[r * 3 + 1] * p[j + 1] + wr[r * 3 + 2] * p[j + 2];
    }
}

// ============================================================
// Scalar-store transposed+swizzled GEMM core (R5-verified) — lngemm only.
// ============================================================
template <int COUT>
__device__ __forceinline__ void gemm_core_tr_sc(
    const unsigned short* BsT,
    const unsigned short* __restrict__ W,     // (COUT, 128) bf16, row-major
    unsigned short* __restrict__ OutB,        // already + b*COUT*NP, channel-major
    int n0, int tid)
{
    const int lane = tid & 63;
    const int wid  = tid >> 6;
    const int ln16 = lane & 15, quad = lane >> 4;
    const int wy = wid >> 1, wx = wid & 1;
    const char* bs = (const char*)BsT;
    const int swz = (ln16 & 7) << 4;
    int rbase[4];
    #pragma unroll
    for (int nt = 0; nt < 4; ++nt) {
        int n = wx * 64 + nt * 16 + ln16;
        rbase[nt] = n * 256 + quad * 16;
    }

    for (int cc = 0; cc < COUT / 128; ++cc) {
        const int m0 = cc * 128;
        f32x4 acc[4][4];
        #pragma unroll
        for (int i = 0; i < 4; ++i)
            #pragma unroll
            for (int j = 0; j < 4; ++j) acc[i][j] = f32x4{0.f, 0.f, 0.f, 0.f};

        #pragma unroll
        for (int k0 = 0; k0 < 128; k0 += 32) {
            bf16x8 afr[4], bfr[4];
            #pragma unroll
            for (int mt = 0; mt < 4; ++mt) {
                int m = m0 + wy * 64 + mt * 16 + ln16;
                uint4 v = *(const uint4*)(W + (size_t)m * 128 + k0 + quad * 8);
                afr[mt] = *(bf16x8*)&v;
            }
            #pragma unroll
            for (int nt = 0; nt < 4; ++nt) {
                uint4 v = *(const uint4*)(bs + ((rbase[nt] + k0 * 2) ^ swz));
                bfr[nt] = *(bf16x8*)&v;
            }
            #pragma unroll
            for (int mt = 0; mt < 4; ++mt)
                #pragma unroll
                for (int nt = 0; nt < 4; ++nt)
                    acc[mt][nt] = __builtin_amdgcn_mfma_f32_16x16x32_bf16(
                        afr[mt], bfr[nt], acc[mt][nt], 0, 0, 0);
        }
        #pragma unroll
        for (int mt = 0; mt < 4; ++mt)
            #pragma unroll
            for (int nt = 0; nt < 4; ++nt) {
                int co0 = m0 + wy * 64 + mt * 16 + quad * 4;
                int n = n0 + wx * 64 + nt * 16 + ln16;
                #pragma unroll
                for (int r = 0; r < 4; ++r)
                    OutB[(size_t)(co0 + r) * NP + n] = f2b(acc[mt][nt][r]);
            }
    }
}

// ============================================================
// Vector-store transposed+swizzled GEMM core (R9-verified) — lngemm2/g1.
// ============================================================
template <int COUT>
__device__ __forceinline__ void gemm_core_tr_v(
    const unsigned short* BsT,
    unsigned short* St,                        // [64*136]
    const unsigned short* __restrict__ W,      // (COUT, 128) bf16, row-major
    unsigned short* __restrict__ OutB,         // already + b*COUT*NP
    int n0, int tid)
{
    const int lane = tid & 63;
    const int wid  = tid >> 6;
    const int ln16 = lane & 15, quad = lane >> 4;
    const int wy = wid >> 1, wx = wid & 1;
    const char* bs = (const char*)BsT;
    const int swz = (ln16 & 7) << 4;
    int rbase[4];
    #pragma unroll
    for (int nt = 0; nt < 4; ++nt) {
        int n = wx * 64 + nt * 16 + ln16;
        rbase[nt] = n * 256 + quad * 16;
    }

    for (int cc = 0; cc < COUT / 128; ++cc) {
        const int m0 = cc * 128;
        f32x4 acc[4][4];
        #pragma unroll
        for (int i = 0; i < 4; ++i)
            #pragma unroll
            for (int j = 0; j < 4; ++j) acc[i][j] = f32x4{0.f, 0.f, 0.f, 0.f};

        #pragma unroll
        for (int k0 = 0; k0 < 128; k0 += 32) {
            bf16x8 afr[4], bfr[4];
            #pragma unroll
            for (int mt = 0; mt < 4; ++mt) {
                int m = m0 + wy * 64 + mt * 16 + ln16;
                uint4 v = *(const uint4*)(W + (size_t)m * 128 + k0 + quad * 8);
                afr[mt] = *(bf16x8*)&v;
            }
            #pragma unroll
            for (int nt = 0; nt < 4; ++nt) {
                uint4 v = *(const uint4*)(bs + ((rbase[nt] + k0 * 2) ^ swz));
                bfr[nt] = *(bf16x8*)&v;
            }
            #pragma unroll
            for (int mt = 0; mt < 4; ++mt)
                #pragma unroll
                for (int nt = 0; nt < 4; ++nt)
                    acc[mt][nt] = __builtin_amdgcn_mfma_f32_16x16x32_bf16(
                        afr[mt], bfr[nt], acc[mt][nt], 0, 0, 0);
        }
        #pragma unroll
        for (int h = 0; h < 2; ++h) {
            if (wy == h) {
                #pragma unroll
                for (int mt = 0; mt < 4; ++mt) {
                    int lr0 = mt * 16 + quad * 4;
                    #pragma unroll
                    for (int nt = 0; nt < 4; ++nt) {
                        int nn = wx * 64 + nt * 16 + ln16;
                        #pragma unroll
                        for (int r = 0; r < 4; ++r)
                            St[(lr0 + r) * 136 + nn] = f2b(acc[mt][nt][r]);
                    }
                }
            }
            __syncthreads();
            #pragma unroll
            for (int i = 0; i < 4; ++i) {
                int flat = tid + i * 256;    // 0..1023
                int row = flat >> 4;         // 0..63
                int g = flat & 15;           // 8-px group (128 px)
                uint4 v = *(const uint4*)(&St[row * 136 + g * 8]);
                *(uint4*)(&OutB[(size_t)(m0 + h * 64 + row) * NP + n0 + g * 8]) = v;
            }
            __syncthreads();
        }
    }
}

// ---------- fused LN(channel) + 1x1-conv GEMM (R5 monolith, fp32 in) ----------
template <int COUT>
__global__ __launch_bounds__(256)
void lngemm_kernel(const float* __restrict__ x,              // (nb, C, NP) fp32
                   const unsigned short* __restrict__ lg,
                   const unsigned short* __restrict__ lb,
                   const unsigned short* __restrict__ W,     // (COUT, 128) bf16
                   unsigned short* __restrict__ Out)         // (nb, COUT, NP) bf16
{
    __shared__ unsigned short BsT[128 * 128];
    __shared__ float Ssum[8][128], Ssq[8][128], Mu[128], Rs[128];
    const int tid = threadIdx.x;
    const int b = blockIdx.y;
    const int n0 = blockIdx.x * 128;
    const int pxg = tid & 31;       // 4 consecutive pixels
    const int cseg = tid >> 5;      // 16 channels
    const float* xb = x + (size_t)b * C * NP + n0 + pxg * 4;

    f32x4 hv[16];
    f32x4 vs = f32x4{0.f, 0.f, 0.f, 0.f}, vq = f32x4{0.f, 0.f, 0.f, 0.f};
    #pragma unroll
    for (int i = 0; i < 16; ++i) {
        f32x4 v = *(const f32x4*)(xb + (size_t)(cseg * 16 + i) * NP);
        hv[i] = v; vs += v; vq += v * v;
    }
    #pragma unroll
    for (int j = 0; j < 4; ++j) {
        Ssum[cseg][pxg * 4 + j] = vs[j];
        Ssq[cseg][pxg * 4 + j]  = vq[j];
    }
    __syncthreads();
    if (tid < 128) {
        float s = 0.f, q = 0.f;
        #pragma unroll
        for (int e = 0; e < 8; ++e) { s += Ssum[e][tid]; q += Ssq[e][tid]; }
        float mu = s * (1.f / 128.f);
        float var = q * (1.f / 128.f) - mu * mu;
        Mu[tid] = mu;
        Rs[tid] = rsqrtf(fmaxf(var, 0.f) + 1e-5f);
    }
    __syncthreads();
    f32x4 mu4 = *(const f32x4*)(&Mu[pxg * 4]);
    f32x4 rs4 = *(const f32x4*)(&Rs[pxg * 4]);

    float gwv[16], bwv[16];
    #pragma unroll
    for (int i = 0; i < 16; ++i) {
        gwv[i] = b2f(lg[cseg * 16 + i]);
        bwv[i] = b2f(lb[cseg * 16 + i]);
    }

    char* p = (char*)BsT;
    #pragma unroll
    for (int j = 0; j < 4; ++j) {
        int n = pxg * 4 + j;
        union { uint4 v[2]; unsigned short u[16]; } o;
        #pragma unroll
        for (int i = 0; i < 16; ++i)
            o.u[i] = f2b((hv[i][j] - mu4[j]) * rs4[j] * gwv[i] + bwv[i]);
        int base = n * 256 + cseg * 32;
        int sw = (n & 7) << 4;
        *(uint4*)(p + (base ^ sw))        = o.v[0];
        *(uint4*)(p + ((base + 16) ^ sw)) = o.v[1];
    }
    __syncthreads();
    gemm_core_tr_sc<COUT>(BsT, W, Out + (size_t)b * COUT * NP, n0, tid);
}

// ---------- fused LN2 (bf16 trunk in) + g1 GEMM, vector epilogue ----------
// Replaces projln's pass B + y2 tensor + old g1 staging.
template <int COUT>
__global__ __launch_bounds__(256)
void lngemm2_kernel(const unsigned short* __restrict__ xm,   // (nb,128,NP) bf16 trunk
                    const unsigned short* __restrict__ lg,
                    const unsigned short* __restrict__ lb,
                    const unsigned short* __restrict__ W,    // (COUT,128) bf16
                    unsigned short* __restrict__ Out)        // (nb,COUT,NP) bf16
{
    __shared__ unsigned short BsT[128 * 128];
    __shared__ unsigned short St[64 * 136];
    __shared__ float LSum[4][128], LSq[4][128], Mu[128], Rs[128];
    const int tid = threadIdx.x;
    const int b = blockIdx.y;
    const int n0 = blockIdx.x * 128;
    const int pxg = tid & 15;        // 8 px: px0 = pxg*8
    const int cseg = tid >> 4;       // 16 segs x 8 ch
    const int lane = tid & 63;
    const unsigned short* xb = xm + (size_t)b * C * NP + n0 + pxg * 8;

    union { uint4 v; unsigned short u[8]; } hv[8];
    float s[8], q[8];
    #pragma unroll
    for (int j = 0; j < 8; ++j) { s[j] = 0.f; q[j] = 0.f; }
    #pragma unroll
    for (int i = 0; i < 8; ++i) {
        hv[i].v = *(const uint4*)(xb + (size_t)(cseg * 8 + i) * NP);
        #pragma unroll
        for (int j = 0; j < 8; ++j) {
            float v = b2f(hv[i].u[j]);
            s[j] += v; q[j] += v * v;
        }
    }
    // reduce over csegs: 4 in-wave (lane>>4), then 4 wave partials
    #pragma unroll
    for (int j = 0; j < 8; ++j) {
        s[j] += __shfl_xor(s[j], 16, 64); q[j] += __shfl_xor(q[j], 16, 64);
        s[j] += __shfl_xor(s[j], 32, 64); q[j] += __shfl_xor(q[j], 32, 64);
    }
    if (lane < 16) {
        int wv = tid >> 6;
        #pragma unroll
        for (int j = 0; j < 8; ++j) {
            LSum[wv][pxg * 8 + j] = s[j];
            LSq[wv][pxg * 8 + j]  = q[j];
        }
    }
    __syncthreads();
    if (tid < 128) {
        float ss = LSum[0][tid] + LSum[1][tid] + LSum[2][tid] + LSum[3][tid];
        float qq = LSq[0][tid] + LSq[1][tid] + LSq[2][tid] + LSq[3][tid];
        float mu = ss * (1.f / 128.f);
        float var = qq * (1.f / 128.f) - mu * mu;
        Mu[tid] = mu; Rs[tid] = rsqrtf(fmaxf(var, 0.f) + 1e-5f);
    }
    __syncthreads();

    float gwv[8], bwv[8];
    #pragma unroll
    for (int i = 0; i < 8; ++i) {
        gwv[i] = b2f(lg[cseg * 8 + i]);
        bwv[i] = b2f(lb[cseg * 8 + i]);
    }
    char* p = (char*)BsT;
    #pragma unroll
    for (int j = 0; j < 8; ++j) {
        int n = pxg * 8 + j;
        float mu = Mu[n], rs = Rs[n];
        union { uint4 v; unsigned short u[8]; } o;
        #pragma unroll
        for (int i = 0; i < 8; ++i)
            o.u[i] = f2b((b2f(hv[i].u[j]) - mu) * rs * gwv[i] + bwv[i]);
        *(uint4*)(p + ((n * 256 + cseg * 16) ^ ((n & 7) << 4))) = o.v;
    }
    __syncthreads();
    gemm_core_tr_v<COUT>(BsT, St, W, Out + (size_t)b * COUT * NP, n0, tid);
}

// ---------- FUSED dwconv3(q,k) + Gram partial + sumsq partial ----------
__global__ __launch_bounds__(256)
void dwqkgram_kernel(const unsigned short* __restrict__ big,   // (nb,384,NP)
                     const unsigned short* __restrict__ w9,    // qkv_d_w (384*9)
                     float* __restrict__ Spart,                // [bh][32][256]
                     float* __restrict__ Npart)                // [bh][32][32]
{
    __shared__ unsigned short qs_[16 * 520];
    __shared__ unsigned short ks_[16 * 520];
    __shared__ float Sred[4][256];
    const int h = blockIdx.x, b = blockIdx.y, sp = blockIdx.z;
    const int tid = threadIdx.x;
    const int wid = tid >> 6, lane = tid & 63;
    const int xi = (tid & 15) * 8;
    const int yr = (tid >> 4) & 3;       // row within slab
    const int y  = sp * 4 + yr;          // image row
    const int bh = b * NH + h;
    float* Np = Npart + ((size_t)bh * 32 + sp) * 32;

    #pragma unroll
    for (int p = 0; p < 4; ++p) {
        int qc = p * 4 + wid;            // local channel 0..15, one per wave
        #pragma unroll
        for (int s = 0; s < 2; ++s) {    // 0 = q, 1 = k
            int ch = s * 128 + h * 16 + qc;
            const unsigned short* base = big + ((size_t)b * 384 + ch) * NP + y * 128 + xi;
            float wr[9];
            #pragma unroll
            for (int i = 0; i < 9; ++i) wr[i] = b2f(w9[ch * 9 + i]);
            float o[8];
            dw8(base, y, xi, wr, o);
            union { uint4 v; unsigned short u[8]; } res;
            float ss = 0.f;
            #pragma unroll
            for (int j = 0; j < 8; ++j) {
                res.u[j] = f2b(o[j]);
                float vv = b2f(res.u[j]);
                ss += vv * vv;
            }
            unsigned short* tile = s ? ks_ : qs_;
            *(uint4*)(&tile[qc * 520 + yr * 128 + xi]) = res.v;
            #pragma unroll
            for (int od = 32; od > 0; od >>= 1) ss += __shfl_xor(ss, od, 64);
            if (lane == 0) Np[s * 16 + qc] = ss;
        }
    }
    __syncthreads();

    const int ln16 = lane & 15, quad = lane >> 4;
    f32x4 acc = f32x4{0.f, 0.f, 0.f, 0.f};
    #pragma unroll
    for (int i = 0; i < 4; ++i) {
        int off = wid * 128 + i * 32 + quad * 8;
        uint4 qv = *(const uint4*)(&qs_[ln16 * 520 + off]);
        uint4 kv = *(const uint4*)(&ks_[ln16 * 520 + off]);
        acc = __builtin_amdgcn_mfma_f32_16x16x32_bf16(*(bf16x8*)&qv, *(bf16x8*)&kv, acc, 0, 0, 0);
    }
    #pragma unroll
    for (int r = 0; r < 4; ++r) Sred[wid][(quad * 4 + r) * 16 + ln16] = acc[r];
    __syncthreads();
    float ssum = Sred[0][tid] + Sred[1][tid] + Sred[2][tid] + Sred[3][tid];
    Spart[((size_t)bh * 32 + sp) * 256 + tid] = ssum;
}

// ---------- softmax + fused W' = proj x blockdiag(P) ----------
__global__ __launch_bounds__(256)
void softwp_kernel(const float* __restrict__ Spart, const float* __restrict__ Npart,
                   const unsigned short* __restrict__ temp,
                   const unsigned short* __restrict__ proj,   // (128,128) bf16
                   unsigned short* __restrict__ W2)           // (nb,128,128) bf16
{
    __shared__ float Ps[256];
    int bh = blockIdx.x;
    int b = bh >> 3, h = bh & 7;
    int t = threadIdx.x;            // 256 = 16x16
    int dq = t >> 4, dk = t & 15;
    float sacc = 0.f;
    const float* Sp = Spart + (size_t)bh * 32 * 256;
    #pragma unroll
    for (int j = 0; j < 32; ++j) sacc += Sp[j * 256 + t];
    const float* Np = Npart + (size_t)bh * 32 * 32;
    float sq = 0.f, sk = 0.f;
    #pragma unroll
    for (int sp = 0; sp < 32; ++sp) { sq += Np[sp * 32 + dq]; sk += Np[sp * 32 + 16 + dk]; }
    float nq = fmaxf(sqrtf(sq), 1e-12f);
    float nk = fmaxf(sqrtf(sk), 1e-12f);
    float v = sacc / (nq * nk) * b2f(temp[h]);
    float m = v;
    #pragma unroll
    for (int o = 8; o > 0; o >>= 1) m = fmaxf(m, __shfl_xor(m, o, 16));
    float e = __expf(v - m);
    float s = e;
    #pragma unroll
    for (int o = 8; o > 0; o >>= 1) s += __shfl_xor(s, o, 16);
    Ps[t] = e / s;                 // P[dq][dk]
    __syncthreads();

    int co = t >> 1;
    int eo = (t & 1) * 8;
    union { uint4 v[2]; unsigned short u[16]; } pw;
    pw.v[0] = *(const uint4*)(proj + (size_t)co * 128 + h * 16);
    pw.v[1] = *(const uint4*)(proj + (size_t)co * 128 + h * 16 + 8);
    float prw[16];
    #pragma unroll
    for (int d = 0; d < 16; ++d) prw[d] = b2f(pw.u[d]);
    union { uint4 v; unsigned short u[8]; } o8;
    #pragma unroll
    for (int j = 0; j < 8; ++j) {
        int ee = eo + j;
        float s2 = 0.f;
        #pragma unroll
        for (int d = 0; d < 16; ++d) s2 += prw[d] * Ps[d * 16 + ee];
        o8.u[j] = f2b(s2);
    }
    *(uint4*)(W2 + ((size_t)b * 128 + co) * 128 + h * 16 + eo) = o8.v;
}

// ---------- proj' GEMM (W2[b] x dw-v IN-BLOCK) + fp32 residual -> bf16 trunk ----------
// LN2 removed (moved into lngemm2). Vector epilogue via Stf alias of Bs.
__global__ __launch_bounds__(256)
void projln_kernel(const unsigned short* __restrict__ W2,    // (nb,128,128) bf16
                   const unsigned short* __restrict__ big,   // (nb,384,NP) bf16
                   const unsigned short* __restrict__ w9,    // qkv_d_w
                   const float* __restrict__ Res,            // x fp32 (nb,128,NP)
                   unsigned short* __restrict__ Xmid)        // bf16 trunk out
{
    __shared__ unsigned short Bs[128][130];
    float* Stf = (float*)Bs;             // epilogue alias (32*132*4 = 16.9KB)
    const int tid = threadIdx.x;
    const int b = blockIdx.y;
    const int y = blockIdx.x;            // image row
    const int n0 = y * 128;
    const unsigned short* Wb = W2 + (size_t)b * 16384;

    // ---- phase 0: dw-conv v -> Bs (8 passes x 16 channels) ----
    {
        const int xi = (tid & 15) * 8;
        const int crow = tid >> 4;       // 0..15
        #pragma unroll
        for (int p = 0; p < 8; ++p) {
            int c = p * 16 + crow;
            int ch = 256 + c;
            const unsigned short* base = big + ((size_t)b * 384 + ch) * NP + n0 + xi;
            float wr[9];
            #pragma unroll
            for (int i = 0; i < 9; ++i) wr[i] = b2f(w9[ch * 9 + i]);
            float o[8];
            dw8(base, y, xi, wr, o);
            union { uint4 v; unsigned int d[4]; unsigned short u[8]; } res;
            #pragma unroll
            for (int j = 0; j < 8; ++j) res.u[j] = f2b(o[j]);
            unsigned int* d = (unsigned int*)&Bs[c][xi];   // 4B-aligned (260B rows)
            d[0] = res.d[0]; d[1] = res.d[1]; d[2] = res.d[2]; d[3] = res.d[3];
        }
    }
    __syncthreads();

    const int lane = tid & 63, wid = tid >> 6;
    const int ln16 = lane & 15, quad = lane >> 4;
    const int wy = wid >> 1, wx = wid & 1;

    f32x4 acc[4][4];
    #pragma unroll
    for (int i = 0; i < 4; ++i)
        #pragma unroll
        for (int j = 0; j < 4; ++j) acc[i][j] = f32x4{0.f, 0.f, 0.f, 0.f};

    #pragma unroll
    for (int k0 = 0; k0 < 128; k0 += 32) {
        bf16x8 afr[4], bfr[4];
        #pragma unroll
        for (int mt = 0; mt < 4; ++mt) {
            int m = wy * 64 + mt * 16 + ln16;
            uint4 v = *(const uint4*)(Wb + (size_t)m * 128 + k0 + quad * 8);
            afr[mt] = *(bf16x8*)&v;
        }
        #pragma unroll
        for (int nt = 0; nt < 4; ++nt) {
            int n = wx * 64 + nt * 16 + ln16;
            union { bf16x8 v; unsigned short u[8]; } tmp;
            #pragma unroll
            for (int j = 0; j < 8; ++j) tmp.u[j] = Bs[k0 + quad * 8 + j][n];
            bfr[nt] = tmp.v;
        }
        #pragma unroll
        for (int mt = 0; mt < 4; ++mt)
            #pragma unroll
            for (int nt = 0; nt < 4; ++nt)
                acc[mt][nt] = __builtin_amdgcn_mfma_f32_16x16x32_bf16(
                    afr[mt], bfr[nt], acc[mt][nt], 0, 0, 0);
    }
    __syncthreads();   // all Bs reads done before aliasing as Stf

    // ---- epilogue: 4 passes of 32 co-rows; vector Res read + bf16 trunk store ----
    size_t base = (size_t)b * 128 * NP;
    #pragma unroll
    for (int mt = 0; mt < 4; ++mt) {
        int lr = wy * 16 + quad * 4;            // local row base 0..31
        #pragma unroll
        for (int nt = 0; nt < 4; ++nt) {
            int nn = wx * 64 + nt * 16 + ln16;
            #pragma unroll
            for (int r = 0; r < 4; ++r)
                Stf[(lr + r) * 132 + nn] = acc[mt][nt][r];
        }
        __syncthreads();
        #pragma unroll
        for (int i = 0; i < 4; ++i) {
            int flat = tid + i * 256;           // 0..1023
            int row = flat >> 5;                // 0..31
            int g = flat & 31;                  // 4-px group
            f32x4 v = *(const f32x4*)(&Stf[row * 132 + g * 4]);
            int absrow = (row >> 4) * 64 + mt * 16 + (row & 15);
            size_t idx = base + (size_t)absrow * NP + n0 + g * 4;
            f32x4 rv = *(const f32x4*)(Res + idx);
            union { uint2 v2; unsigned short u[4]; } o;
            #pragma unroll
            for (int k = 0; k < 4; ++k) o.u[k] = f2b(rv[k] + v[k]);
            *(uint2*)(Xmid + idx) = o.v2;
        }
        __syncthreads();
    }
}

// ---------- g2 GEMM (K=256) + bf16 residual -> fp32 out, vectorized epilogue ----------
template <int K>
__global__ __launch_bounds__(256)
void gemm_pconv(const unsigned short* __restrict__ W,   // (Cout, K) bf16
                const unsigned short* __restrict__ X,   // (nb, K, NP) bf16
                float* __restrict__ Out,
                const unsigned short* __restrict__ Res, // bf16 trunk
                int Cout)
{
    __shared__ unsigned short Bs[32][130];
    __shared__ float Stf[32 * 132];               // 32 co x 128 px fp32
    const int tid = threadIdx.x;
    const int b = blockIdx.z;
    const int n0 = blockIdx.x * 128;
    const int m0 = blockIdx.y * 128;
    const unsigned short* Xb = X + (size_t)b * K * NP;
    const int wid = tid >> 6;
    const int lane = tid & 63;
    const int ln16 = lane & 15;
    const int quad = lane >> 4;
    const int wy = wid >> 1;
    const int wx = wid & 1;

    f32x4 acc[4][4];
    #pragma unroll
    for (int i = 0; i < 4; ++i)
        #pragma unroll
        for (int j = 0; j < 4; ++j)
            acc[i][j] = f32x4{0.f, 0.f, 0.f, 0.f};

    for (int k0 = 0; k0 < K; k0 += 32) {
        #pragma unroll
        for (int r = 0; r < 2; ++r) {
            int flat = tid + r * 256;
            int kk = flat >> 4;
            int nn = (flat & 15) * 8;
            uint4 v = *(const uint4*)(Xb + (size_t)(k0 + kk) * NP + n0 + nn);
            unsigned int* d = (unsigned int*)&Bs[kk][nn];
            d[0] = v.x; d[1] = v.y; d[2] = v.z; d[3] = v.w;
        }
        __syncthreads();

        bf16x8 afr[4];
        #pragma unroll
        for (int mt = 0; mt < 4; ++mt) {
            int m = m0 + wy * 64 + mt * 16 + ln16;
            uint4 v = *(const uint4*)(W + (size_t)m * K + k0 + quad * 8);
            afr[mt] = *(bf16x8*)&v;
        }
        bf16x8 bfr[4];
        #pragma unroll
        for (int nt = 0; nt < 4; ++nt) {
            int n = wx * 64 + nt * 16 + ln16;
            union { bf16x8 v; unsigned short u[8]; } tmp;
            #pragma unroll
            for (int j = 0; j < 8; ++j) tmp.u[j] = Bs[quad * 8 + j][n];
            bfr[nt] = tmp.v;
        }
        #pragma unroll
        for (int mt = 0; mt < 4; ++mt)
            #pragma unroll
            for (int nt = 0; nt < 4; ++nt)
                acc[mt][nt] = __builtin_amdgcn_mfma_f32_16x16x32_bf16(
                    afr[mt], bfr[nt], acc[mt][nt], 0, 0, 0);
        __syncthreads();
    }

    size_t outbase = (size_t)b * Cout * NP;
    #pragma unroll
    for (int mt = 0; mt < 4; ++mt) {
        int lr = wy * 16 + quad * 4;            // local row base 0..31
        #pragma unroll
        for (int nt = 0; nt < 4; ++nt) {
            int nn = wx * 64 + nt * 16 + ln16;
            #pragma unroll
            for (int r = 0; r < 4; ++r)
                Stf[(lr + r) * 132 + nn] = acc[mt][nt][r];
        }
        __syncthreads();
        #pragma unroll
        for (int i = 0; i < 4; ++i) {
            int flat = tid + i * 256;           // 0..1023
            int row = flat >> 5;                // 0..31
            int g = flat & 31;                  // 4-px group
            f32x4 v = *(const f32x4*)(&Stf[row * 132 + g * 4]);
            int absrow = m0 + (row >> 4) * 64 + mt * 16 + (row & 15);
            size_t idx = outbase + (size_t)absrow * NP + n0 + g * 4;
            union { uint2 u2; unsigned short u[4]; } rv;
            rv.u2 = *(const uint2*)(Res + idx);
            f32x4 o;
            #pragma unroll
            for (int k = 0; k < 4; ++k) o[k] = b2f(rv.u[k]) + v[k];
            *(f32x4*)(Out + idx) = o;
        }
        __syncthreads();
    }
}

// ---------- fused dw3x3 + fast-GELU gate ----------
__global__ __launch_bounds__(256)
void dwgelu_kernel(const unsigned short* __restrict__ hdn,
                   const unsigned short* __restrict__ w9,
                   unsigned short* __restrict__ g)
{
    int t = blockIdx.x * 256 + threadIdx.x;
    int xi = (t & 15) * 8;
    int y  = (t >> 4) & 127;
    int bc = t >> 11;
    int c  = bc & 255;
    int b  = bc >> 8;
    const unsigned short* base1 = hdn + ((size_t)b * 512 + c) * NP + y * 128 + xi;
    const unsigned short* base2 = base1 + (size_t)256 * NP;

    float w1[9], w2[9];
    #pragma unroll
    for (int i = 0; i < 9; ++i) {
        w1[i] = b2f(w9[c * 9 + i]);
        w2[i] = b2f(w9[(c + 256) * 9 + i]);
    }

    float a1[8], a2[8];
    dw8(base1, y, xi, w1, a1);
    dw8(base2, y, xi, w2, a2);

    union { uint4 v; unsigned short u[8]; } res;
    #pragma unroll
    for (int j = 0; j < 8; ++j) {
        float u = a1[j];
        float tt = u * (0.7978845608f + 0.0356774081f * u * u);
        float e = __expf(2.f * tt);
        float th = 1.f - 2.f / (e + 1.f);
        float ge = 0.5f * u * (1.f + th);
        res.u[j] = f2b(ge * a2[j]);
    }
    *(uint4*)(g + (size_t)bc * NP + y * 128 + xi) = res.v;
}

// ---------- pipeline ----------
struct Bufs {
    unsigned short* xmid;   // nb*C*NP bf16 (trunk after MDTA, channel-major)
    unsigned short* big;    // nb*512*NP bf16 channel-major (qkv1 / hdn)
    unsigned short* mid;    // nb*256*NP bf16 channel-major (gate out)
    float* Spart;           // nb*NH*32*256
    float* Npart;           // nb*NH*32*32
    unsigned short* W2;     // nb*128*128 bf16 (proj x blockdiag(P))
};

static void run_pipeline(const float* x_f32, float* out_f32,
                         const unsigned short* w,
                         const Bufs& B, int nb, hipStream_t stream)
{
    const unsigned short* ln1_w   = w + 0;
    const unsigned short* ln1_b   = w + 128;
    const unsigned short* temp    = w + 256;
    const unsigned short* qkv_p_w = w + 272;
    const unsigned short* qkv_d_w = w + 49424;
    const unsigned short* proj_w  = w + 52880;
    const unsigned short* ln2_w   = w + 69264;
    const unsigned short* ln2_b   = w + 69392;
    const unsigned short* g1_w    = w + 69520;
    const unsigned short* gd_w    = w + 135056;
    const unsigned short* g2_w    = w + 139664;

    // ---- MDTA ----
    lngemm_kernel<384><<<dim3(NP / 128, nb), 256, 0, stream>>>(x_f32, ln1_w, ln1_b, qkv_p_w, B.big);
    dwqkgram_kernel<<<dim3(NH, nb, 32), 256, 0, stream>>>(B.big, qkv_d_w, B.Spart, B.Npart);
    softwp_kernel<<<nb * NH, 256, 0, stream>>>(B.Spart, B.Npart, temp, proj_w, B.W2);
    projln_kernel<<<dim3(NP / 128, nb), 256, 0, stream>>>(B.W2, B.big, qkv_d_w, x_f32, B.xmid);

    // ---- GDFN ----
    lngemm2_kernel<512><<<dim3(NP / 128, nb), 256, 0, stream>>>(B.xmid, ln2_w, ln2_b, g1_w, B.big);
    dwgelu_kernel<<<nb * 256 * NP / 2048, 256, 0, stream>>>(B.big, gd_w, B.mid);
    gemm_pconv<256><<<dim3(NP / 128, 1, nb), 256, 0, stream>>>(g2_w, B.mid, out_f32, B.xmid, 128);
}

extern "C" void kernel_launch(void* const* d_in, const int* in_sizes, int n_in,
                              void* d_out, int out_size, void* d_ws, size_t ws_size,
                              hipStream_t stream)
{
    (void)in_sizes; (void)n_in; (void)out_size;
    const float* x = (const float*)d_in[0];
    char* ws = (char*)d_ws;

    size_t off = 0;
    unsigned short* wpack = (unsigned short*)(ws + off);
    off += (size_t)kWTotal * 2;
    off = (off + 255) & ~(size_t)255;
    size_t header = off;

    auto layout = [&](int nb, size_t o, Bufs& B) -> size_t {
        B.xmid = (unsigned short*)(ws + o);  o += (size_t)nb * C * NP * 2;
        B.big  = (unsigned short*)(ws + o);  o += (size_t)nb * 512 * NP * 2;
        B.mid  = (unsigned short*)(ws + o);  o += (size_t)nb * 256 * NP * 2;
        B.Spart = (float*)(ws + o);          o += (size_t)nb * NH * 32 * 256 * 4;
        B.Npart = (float*)(ws + o);          o += (size_t)nb * NH * 32 * 32 * 4;
        B.W2   = (unsigned short*)(ws + o);  o += (size_t)nb * 128 * 128 * 2;
        return o;
    };

    Ptr11 P;
    for (int i = 0; i < 11; ++i) P.p[i] = (const float*)d_in[i + 1];
    cvt_w_kernel<<<dim3(256, 11), 256, 0, stream>>>(P, wpack);

    Bufs Bfull;
    size_t need_full = layout(4, header, Bfull);

    if (ws_size >= need_full) {
        run_pipeline(x, (float*)d_out, wpack, Bfull, 4, stream);
    } else {
        Bufs B1;
        layout(1, header, B1);
        for (int b = 0; b < 4; ++b) {
            run_pipeline(x + (size_t)b * C * NP,
                         (float*)d_out + (size_t)b * C * NP,
                         wpack, B1, 1, stream);
        }
    }
}

// Round 13
// 237.476 us; speedup vs baseline: 1.0959x; 1.0307x over previous
//
#include <hip/hip_runtime.h>
#include <cstdint>
#include <cstddef>

// ---------- types / helpers ----------
typedef float f32x4 __attribute__((ext_vector_type(4)));
typedef __bf16 bf16x8 __attribute__((ext_vector_type(8)));

__device__ __forceinline__ float b2f(unsigned short u) {
    union { unsigned int i; float f; } z; z.i = ((unsigned int)u) << 16; return z.f;
}
__device__ __forceinline__ unsigned short f2b(float f) {
    union { float f; unsigned int i; } z; z.f = f;
    unsigned int x = z.i;
    return (unsigned short)((x + 0x7FFFu + ((x >> 16) & 1u)) >> 16);
}

static constexpr int C = 128;
static constexpr int NP = 16384;      // H*W
static constexpr int NH = 8;

// ---------- weight pack: fp32 -> bf16 ----------
struct Ptr11 { const float* p[11]; };
__constant__ int kWN[11]   = {128, 128, 8, 49152, 3456, 16384, 128, 128, 65536, 4608, 32768};
__constant__ int kWOff[11] = {0, 128, 256, 272, 49424, 52880, 69264, 69392, 69520, 135056, 139664};
static constexpr int kWTotal = 172432;

__global__ __launch_bounds__(256)
void cvt_w_kernel(Ptr11 P, unsigned short* __restrict__ dst)
{
    int seg = blockIdx.y;
    int n = kWN[seg];
    int i = blockIdx.x * 256 + threadIdx.x;
    if (i >= n) return;
    dst[kWOff[seg] + i] = f2b(P.p[seg][i]);
}

// ---------- shared dwconv3 row helper: 8 px, halos via width-16 shuffles ----------
__device__ __forceinline__ void dw8(const unsigned short* base, int y, int xi,
                                    const float* wr, float* o)
{
    uint4 rv0 = uint4{0,0,0,0}, rv1, rv2 = uint4{0,0,0,0};
    if (y > 0)   rv0 = *(const uint4*)(base - 128);
    rv1 = *(const uint4*)(base);
    if (y < 127) rv2 = *(const uint4*)(base + 128);
    uint4 rows[3] = {rv0, rv1, rv2};
    #pragma unroll
    for (int j = 0; j < 8; ++j) o[j] = 0.f;
    #pragma unroll
    for (int r = 0; r < 3; ++r) {
        union { uint4 v; unsigned short u[8]; } cv; cv.v = rows[r];
        int lh = __shfl_up((int)cv.u[7], 1, 16);
        int rh = __shfl_down((int)cv.u[0], 1, 16);
        float p[10];
        p[0] = (xi > 0)   ? b2f((unsigned short)lh) : 0.f;
        p[9] = (xi < 120) ? b2f((unsigned short)rh) : 0.f;
        #pragma unroll
        for (int j = 0; j < 8; ++j) p[j + 1] = b2f(cv.u[j]);
        #pragma unroll
        for (int j = 0; j < 8; ++j)
            o[j] += wr[r * 3] * p[j] + wr[r * 3 + 1] * p[j + 1] + wr[r * 3 + 2] * p[j + 2];
    }
}

// ============================================================
// Vector-store transposed+swizzled GEMM core (R9/R12-verified).
// St: 64 co x 128 px staging, row 272B (17x16B).
// ============================================================
template <int COUT>
__device__ __forceinline__ void gemm_core_tr_v(
    const unsigned short* BsT,
    unsigned short* St,                        // [64*136]
    const unsigned short* __restrict__ W,      // (COUT, 128) bf16, row-major
    unsigned short* __restrict__ OutB,         // already + b*COUT*NP
    int n0, int tid)
{
    const int lane = tid & 63;
    const int wid  = tid >> 6;
    const int ln16 = lane & 15, quad = lane >> 4;
    const int wy = wid >> 1, wx = wid & 1;
    const char* bs = (const char*)BsT;
    const int swz = (ln16 & 7) << 4;
    int rbase[4];
    #pragma unroll
    for (int nt = 0; nt < 4; ++nt) {
        int n = wx * 64 + nt * 16 + ln16;
        rbase[nt] = n * 256 + quad * 16;
    }

    for (int cc = 0; cc < COUT / 128; ++cc) {
        const int m0 = cc * 128;
        f32x4 acc[4][4];
        #pragma unroll
        for (int i = 0; i < 4; ++i)
            #pragma unroll
            for (int j = 0; j < 4; ++j) acc[i][j] = f32x4{0.f, 0.f, 0.f, 0.f};

        #pragma unroll
        for (int k0 = 0; k0 < 128; k0 += 32) {
            bf16x8 afr[4], bfr[4];
            #pragma unroll
            for (int mt = 0; mt < 4; ++mt) {
                int m = m0 + wy * 64 + mt * 16 + ln16;
                uint4 v = *(const uint4*)(W + (size_t)m * 128 + k0 + quad * 8);
                afr[mt] = *(bf16x8*)&v;
            }
            #pragma unroll
            for (int nt = 0; nt < 4; ++nt) {
                uint4 v = *(const uint4*)(bs + ((rbase[nt] + k0 * 2) ^ swz));
                bfr[nt] = *(bf16x8*)&v;
            }
            #pragma unroll
            for (int mt = 0; mt < 4; ++mt)
                #pragma unroll
                for (int nt = 0; nt < 4; ++nt)
                    acc[mt][nt] = __builtin_amdgcn_mfma_f32_16x16x32_bf16(
                        afr[mt], bfr[nt], acc[mt][nt], 0, 0, 0);
        }
        #pragma unroll
        for (int h = 0; h < 2; ++h) {
            if (wy == h) {
                #pragma unroll
                for (int mt = 0; mt < 4; ++mt) {
                    int lr0 = mt * 16 + quad * 4;
                    #pragma unroll
                    for (int nt = 0; nt < 4; ++nt) {
                        int nn = wx * 64 + nt * 16 + ln16;
                        #pragma unroll
                        for (int r = 0; r < 4; ++r)
                            St[(lr0 + r) * 136 + nn] = f2b(acc[mt][nt][r]);
                    }
                }
            }
            __syncthreads();
            #pragma unroll
            for (int i = 0; i < 4; ++i) {
                int flat = tid + i * 256;    // 0..1023
                int row = flat >> 4;         // 0..63
                int g = flat & 15;           // 8-px group (128 px)
                uint4 v = *(const uint4*)(&St[row * 136 + g * 8]);
                *(uint4*)(&OutB[(size_t)(m0 + h * 64 + row) * NP + n0 + g * 8]) = v;
            }
            __syncthreads();
        }
    }
}

// ---------- fused LN(channel) + 1x1-conv GEMM; vector epilogue, aliased LDS ----------
// Stats region (9216 B) is dead after BsT write + barrier; St (17408 B) first
// written after that barrier -> union them. LDS = 32768 + 17408 = 50176 B (3 blk/CU).
template <int COUT>
__global__ __launch_bounds__(256)
void lngemm_kernel(const float* __restrict__ x,              // (nb, C, NP) fp32
                   const unsigned short* __restrict__ lg,
                   const unsigned short* __restrict__ lb,
                   const unsigned short* __restrict__ W,     // (COUT, 128) bf16
                   unsigned short* __restrict__ Out)         // (nb, COUT, NP) bf16
{
    __shared__ unsigned short BsT[128 * 128];
    __shared__ float SS[4352];     // union: stats (2304 f) / St (8704 ushort)
    float (*Ssum)[128] = (float(*)[128])SS;
    float (*Ssq)[128]  = (float(*)[128])(SS + 1024);
    float* Mu = SS + 2048;
    float* Rs = SS + 2176;
    unsigned short* St = (unsigned short*)SS;

    const int tid = threadIdx.x;
    const int b = blockIdx.y;
    const int n0 = blockIdx.x * 128;
    const int pxg = tid & 31;       // 4 consecutive pixels
    const int cseg = tid >> 5;      // 16 channels
    const float* xb = x + (size_t)b * C * NP + n0 + pxg * 4;

    f32x4 hv[16];
    f32x4 vs = f32x4{0.f, 0.f, 0.f, 0.f}, vq = f32x4{0.f, 0.f, 0.f, 0.f};
    #pragma unroll
    for (int i = 0; i < 16; ++i) {
        f32x4 v = *(const f32x4*)(xb + (size_t)(cseg * 16 + i) * NP);
        hv[i] = v; vs += v; vq += v * v;
    }
    #pragma unroll
    for (int j = 0; j < 4; ++j) {
        Ssum[cseg][pxg * 4 + j] = vs[j];
        Ssq[cseg][pxg * 4 + j]  = vq[j];
    }
    __syncthreads();
    if (tid < 128) {
        float s = 0.f, q = 0.f;
        #pragma unroll
        for (int e = 0; e < 8; ++e) { s += Ssum[e][tid]; q += Ssq[e][tid]; }
        float mu = s * (1.f / 128.f);
        float var = q * (1.f / 128.f) - mu * mu;
        Mu[tid] = mu;
        Rs[tid] = rsqrtf(fmaxf(var, 0.f) + 1e-5f);
    }
    __syncthreads();
    f32x4 mu4 = *(const f32x4*)(&Mu[pxg * 4]);
    f32x4 rs4 = *(const f32x4*)(&Rs[pxg * 4]);

    float gwv[16], bwv[16];
    #pragma unroll
    for (int i = 0; i < 16; ++i) {
        gwv[i] = b2f(lg[cseg * 16 + i]);
        bwv[i] = b2f(lb[cseg * 16 + i]);
    }

    char* p = (char*)BsT;
    #pragma unroll
    for (int j = 0; j < 4; ++j) {
        int n = pxg * 4 + j;
        union { uint4 v[2]; unsigned short u[16]; } o;
        #pragma unroll
        for (int i = 0; i < 16; ++i)
            o.u[i] = f2b((hv[i][j] - mu4[j]) * rs4[j] * gwv[i] + bwv[i]);
        int base = n * 256 + cseg * 32;
        int sw = (n & 7) << 4;
        *(uint4*)(p + (base ^ sw))        = o.v[0];
        *(uint4*)(p + ((base + 16) ^ sw)) = o.v[1];
    }
    __syncthreads();   // last read of Mu/Rs above; St first written after this
    gemm_core_tr_v<COUT>(BsT, St, W, Out + (size_t)b * COUT * NP, n0, tid);
}

// ---------- fused LN2 (bf16 trunk in) + g1 GEMM, vector epilogue ----------
template <int COUT>
__global__ __launch_bounds__(256)
void lngemm2_kernel(const unsigned short* __restrict__ xm,   // (nb,128,NP) bf16 trunk
                    const unsigned short* __restrict__ lg,
                    const unsigned short* __restrict__ lb,
                    const unsigned short* __restrict__ W,    // (COUT,128) bf16
                    unsigned short* __restrict__ Out)        // (nb,COUT,NP) bf16
{
    __shared__ unsigned short BsT[128 * 128];
    __shared__ unsigned short St[64 * 136];
    __shared__ float LSum[4][128], LSq[4][128], Mu[128], Rs[128];
    const int tid = threadIdx.x;
    const int b = blockIdx.y;
    const int n0 = blockIdx.x * 128;
    const int pxg = tid & 15;        // 8 px: px0 = pxg*8
    const int cseg = tid >> 4;       // 16 segs x 8 ch
    const int lane = tid & 63;
    const unsigned short* xb = xm + (size_t)b * C * NP + n0 + pxg * 8;

    union { uint4 v; unsigned short u[8]; } hv[8];
    float s[8], q[8];
    #pragma unroll
    for (int j = 0; j < 8; ++j) { s[j] = 0.f; q[j] = 0.f; }
    #pragma unroll
    for (int i = 0; i < 8; ++i) {
        hv[i].v = *(const uint4*)(xb + (size_t)(cseg * 8 + i) * NP);
        #pragma unroll
        for (int j = 0; j < 8; ++j) {
            float v = b2f(hv[i].u[j]);
            s[j] += v; q[j] += v * v;
        }
    }
    #pragma unroll
    for (int j = 0; j < 8; ++j) {
        s[j] += __shfl_xor(s[j], 16, 64); q[j] += __shfl_xor(q[j], 16, 64);
        s[j] += __shfl_xor(s[j], 32, 64); q[j] += __shfl_xor(q[j], 32, 64);
    }
    if (lane < 16) {
        int wv = tid >> 6;
        #pragma unroll
        for (int j = 0; j < 8; ++j) {
            LSum[wv][pxg * 8 + j] = s[j];
            LSq[wv][pxg * 8 + j]  = q[j];
        }
    }
    __syncthreads();
    if (tid < 128) {
        float ss = LSum[0][tid] + LSum[1][tid] + LSum[2][tid] + LSum[3][tid];
        float qq = LSq[0][tid] + LSq[1][tid] + LSq[2][tid] + LSq[3][tid];
        float mu = ss * (1.f / 128.f);
        float var = qq * (1.f / 128.f) - mu * mu;
        Mu[tid] = mu; Rs[tid] = rsqrtf(fmaxf(var, 0.f) + 1e-5f);
    }
    __syncthreads();

    float gwv[8], bwv[8];
    #pragma unroll
    for (int i = 0; i < 8; ++i) {
        gwv[i] = b2f(lg[cseg * 8 + i]);
        bwv[i] = b2f(lb[cseg * 8 + i]);
    }
    char* p = (char*)BsT;
    #pragma unroll
    for (int j = 0; j < 8; ++j) {
        int n = pxg * 8 + j;
        float mu = Mu[n], rs = Rs[n];
        union { uint4 v; unsigned short u[8]; } o;
        #pragma unroll
        for (int i = 0; i < 8; ++i)
            o.u[i] = f2b((b2f(hv[i].u[j]) - mu) * rs * gwv[i] + bwv[i]);
        *(uint4*)(p + ((n * 256 + cseg * 16) ^ ((n & 7) << 4))) = o.v;
    }
    __syncthreads();
    gemm_core_tr_v<COUT>(BsT, St, W, Out + (size_t)b * COUT * NP, n0, tid);
}

// ---------- FUSED dwconv3(q,k) + Gram partial + sumsq partial ----------
__global__ __launch_bounds__(256)
void dwqkgram_kernel(const unsigned short* __restrict__ big,   // (nb,384,NP)
                     const unsigned short* __restrict__ w9,    // qkv_d_w (384*9)
                     float* __restrict__ Spart,                // [bh][32][256]
                     float* __restrict__ Npart)                // [bh][32][32]
{
    __shared__ unsigned short qs_[16 * 520];
    __shared__ unsigned short ks_[16 * 520];
    __shared__ float Sred[4][256];
    const int h = blockIdx.x, b = blockIdx.y, sp = blockIdx.z;
    const int tid = threadIdx.x;
    const int wid = tid >> 6, lane = tid & 63;
    const int xi = (tid & 15) * 8;
    const int yr = (tid >> 4) & 3;       // row within slab
    const int y  = sp * 4 + yr;          // image row
    const int bh = b * NH + h;
    float* Np = Npart + ((size_t)bh * 32 + sp) * 32;

    #pragma unroll
    for (int p = 0; p < 4; ++p) {
        int qc = p * 4 + wid;            // local channel 0..15, one per wave
        #pragma unroll
        for (int s = 0; s < 2; ++s) {    // 0 = q, 1 = k
            int ch = s * 128 + h * 16 + qc;
            const unsigned short* base = big + ((size_t)b * 384 + ch) * NP + y * 128 + xi;
            float wr[9];
            #pragma unroll
            for (int i = 0; i < 9; ++i) wr[i] = b2f(w9[ch * 9 + i]);
            float o[8];
            dw8(base, y, xi, wr, o);
            union { uint4 v; unsigned short u[8]; } res;
            float ss = 0.f;
            #pragma unroll
            for (int j = 0; j < 8; ++j) {
                res.u[j] = f2b(o[j]);
                float vv = b2f(res.u[j]);
                ss += vv * vv;
            }
            unsigned short* tile = s ? ks_ : qs_;
            *(uint4*)(&tile[qc * 520 + yr * 128 + xi]) = res.v;
            #pragma unroll
            for (int od = 32; od > 0; od >>= 1) ss += __shfl_xor(ss, od, 64);
            if (lane == 0) Np[s * 16 + qc] = ss;
        }
    }
    __syncthreads();

    const int ln16 = lane & 15, quad = lane >> 4;
    f32x4 acc = f32x4{0.f, 0.f, 0.f, 0.f};
    #pragma unroll
    for (int i = 0; i < 4; ++i) {
        int off = wid * 128 + i * 32 + quad * 8;
        uint4 qv = *(const uint4*)(&qs_[ln16 * 520 + off]);
        uint4 kv = *(const uint4*)(&ks_[ln16 * 520 + off]);
        acc = __builtin_amdgcn_mfma_f32_16x16x32_bf16(*(bf16x8*)&qv, *(bf16x8*)&kv, acc, 0, 0, 0);
    }
    #pragma unroll
    for (int r = 0; r < 4; ++r) Sred[wid][(quad * 4 + r) * 16 + ln16] = acc[r];
    __syncthreads();
    float ssum = Sred[0][tid] + Sred[1][tid] + Sred[2][tid] + Sred[3][tid];
    Spart[((size_t)bh * 32 + sp) * 256 + tid] = ssum;
}

// ---------- softmax + fused W' = proj x blockdiag(P) ----------
__global__ __launch_bounds__(256)
void softwp_kernel(const float* __restrict__ Spart, const float* __restrict__ Npart,
                   const unsigned short* __restrict__ temp,
                   const unsigned short* __restrict__ proj,   // (128,128) bf16
                   unsigned short* __restrict__ W2)           // (nb,128,128) bf16
{
    __shared__ float Ps[256];
    int bh = blockIdx.x;
    int b = bh >> 3, h = bh & 7;
    int t = threadIdx.x;            // 256 = 16x16
    int dq = t >> 4, dk = t & 15;
    float sacc = 0.f;
    const float* Sp = Spart + (size_t)bh * 32 * 256;
    #pragma unroll
    for (int j = 0; j < 32; ++j) sacc += Sp[j * 256 + t];
    const float* Np = Npart + (size_t)bh * 32 * 32;
    float sq = 0.f, sk = 0.f;
    #pragma unroll
    for (int sp = 0; sp < 32; ++sp) { sq += Np[sp * 32 + dq]; sk += Np[sp * 32 + 16 + dk]; }
    float nq = fmaxf(sqrtf(sq), 1e-12f);
    float nk = fmaxf(sqrtf(sk), 1e-12f);
    float v = sacc / (nq * nk) * b2f(temp[h]);
    float m = v;
    #pragma unroll
    for (int o = 8; o > 0; o >>= 1) m = fmaxf(m, __shfl_xor(m, o, 16));
    float e = __expf(v - m);
    float s = e;
    #pragma unroll
    for (int o = 8; o > 0; o >>= 1) s += __shfl_xor(s, o, 16);
    Ps[t] = e / s;                 // P[dq][dk]
    __syncthreads();

    int co = t >> 1;
    int eo = (t & 1) * 8;
    union { uint4 v[2]; unsigned short u[16]; } pw;
    pw.v[0] = *(const uint4*)(proj + (size_t)co * 128 + h * 16);
    pw.v[1] = *(const uint4*)(proj + (size_t)co * 128 + h * 16 + 8);
    float prw[16];
    #pragma unroll
    for (int d = 0; d < 16; ++d) prw[d] = b2f(pw.u[d]);
    union { uint4 v; unsigned short u[8]; } o8;
    #pragma unroll
    for (int j = 0; j < 8; ++j) {
        int ee = eo + j;
        float s2 = 0.f;
        #pragma unroll
        for (int d = 0; d < 16; ++d) s2 += prw[d] * Ps[d * 16 + ee];
        o8.u[j] = f2b(s2);
    }
    *(uint4*)(W2 + ((size_t)b * 128 + co) * 128 + h * 16 + eo) = o8.v;
}

// ---------- proj' GEMM (W2[b] x dw-v IN-BLOCK) + fp32 residual -> bf16 trunk ----------
__global__ __launch_bounds__(256)
void projln_kernel(const unsigned short* __restrict__ W2,    // (nb,128,128) bf16
                   const unsigned short* __restrict__ big,   // (nb,384,NP) bf16
                   const unsigned short* __restrict__ w9,    // qkv_d_w
                   const float* __restrict__ Res,            // x fp32 (nb,128,NP)
                   unsigned short* __restrict__ Xmid)        // bf16 trunk out
{
    __shared__ unsigned short Bs[128][130];
    float* Stf = (float*)Bs;             // epilogue alias
    const int tid = threadIdx.x;
    const int b = blockIdx.y;
    const int y = blockIdx.x;            // image row
    const int n0 = y * 128;
    const unsigned short* Wb = W2 + (size_t)b * 16384;

    // ---- phase 0: dw-conv v -> Bs (8 passes x 16 channels) ----
    {
        const int xi = (tid & 15) * 8;
        const int crow = tid >> 4;       // 0..15
        #pragma unroll
        for (int p = 0; p < 8; ++p) {
            int c = p * 16 + crow;
            int ch = 256 + c;
            const unsigned short* base = big + ((size_t)b * 384 + ch) * NP + n0 + xi;
            float wr[9];
            #pragma unroll
            for (int i = 0; i < 9; ++i) wr[i] = b2f(w9[ch * 9 + i]);
            float o[8];
            dw8(base, y, xi, wr, o);
            union { uint4 v; unsigned int d[4]; unsigned short u[8]; } res;
            #pragma unroll
            for (int j = 0; j < 8; ++j) res.u[j] = f2b(o[j]);
            unsigned int* d = (unsigned int*)&Bs[c][xi];
            d[0] = res.d[0]; d[1] = res.d[1]; d[2] = res.d[2]; d[3] = res.d[3];
        }
    }
    __syncthreads();

    const int lane = tid & 63, wid = tid >> 6;
    const int ln16 = lane & 15, quad = lane >> 4;
    const int wy = wid >> 1, wx = wid & 1;

    f32x4 acc[4][4];
    #pragma unroll
    for (int i = 0; i < 4; ++i)
        #pragma unroll
        for (int j = 0; j < 4; ++j) acc[i][j] = f32x4{0.f, 0.f, 0.f, 0.f};

    #pragma unroll
    for (int k0 = 0; k0 < 128; k0 += 32) {
        bf16x8 afr[4], bfr[4];
        #pragma unroll
        for (int mt = 0; mt < 4; ++mt) {
            int m = wy * 64 + mt * 16 + ln16;
            uint4 v = *(const uint4*)(Wb + (size_t)m * 128 + k0 + quad * 8);
            afr[mt] = *(bf16x8*)&v;
        }
        #pragma unroll
        for (int nt = 0; nt < 4; ++nt) {
            int n = wx * 64 + nt * 16 + ln16;
            union { bf16x8 v; unsigned short u[8]; } tmp;
            #pragma unroll
            for (int j = 0; j < 8; ++j) tmp.u[j] = Bs[k0 + quad * 8 + j][n];
            bfr[nt] = tmp.v;
        }
        #pragma unroll
        for (int mt = 0; mt < 4; ++mt)
            #pragma unroll
            for (int nt = 0; nt < 4; ++nt)
                acc[mt][nt] = __builtin_amdgcn_mfma_f32_16x16x32_bf16(
                    afr[mt], bfr[nt], acc[mt][nt], 0, 0, 0);
    }
    __syncthreads();   // all Bs reads done before aliasing as Stf

    // ---- epilogue: 4 passes of 32 co-rows; vector Res read + bf16 trunk store ----
    size_t base = (size_t)b * 128 * NP;
    #pragma unroll
    for (int mt = 0; mt < 4; ++mt) {
        int lr = wy * 16 + quad * 4;
        #pragma unroll
        for (int nt = 0; nt < 4; ++nt) {
            int nn = wx * 64 + nt * 16 + ln16;
            #pragma unroll
            for (int r = 0; r < 4; ++r)
                Stf[(lr + r) * 132 + nn] = acc[mt][nt][r];
        }
        __syncthreads();
        #pragma unroll
        for (int i = 0; i < 4; ++i) {
            int flat = tid + i * 256;
            int row = flat >> 5;
            int g = flat & 31;
            f32x4 v = *(const f32x4*)(&Stf[row * 132 + g * 4]);
            int absrow = (row >> 4) * 64 + mt * 16 + (row & 15);
            size_t idx = base + (size_t)absrow * NP + n0 + g * 4;
            f32x4 rv = *(const f32x4*)(Res + idx);
            union { uint2 v2; unsigned short u[4]; } o;
            #pragma unroll
            for (int k = 0; k < 4; ++k) o.u[k] = f2b(rv[k] + v[k]);
            *(uint2*)(Xmid + idx) = o.v2;
        }
        __syncthreads();
    }
}

// ---------- g2 GEMM (K=256) + bf16 residual -> fp32 out, vectorized epilogue ----------
template <int K>
__global__ __launch_bounds__(256)
void gemm_pconv(const unsigned short* __restrict__ W,   // (Cout, K) bf16
                const unsigned short* __restrict__ X,   // (nb, K, NP) bf16
                float* __restrict__ Out,
                const unsigned short* __restrict__ Res, // bf16 trunk
                int Cout)
{
    __shared__ unsigned short Bs[32][130];
    __shared__ float Stf[32 * 132];
    const int tid = threadIdx.x;
    const int b = blockIdx.z;
    const int n0 = blockIdx.x * 128;
    const int m0 = blockIdx.y * 128;
    const unsigned short* Xb = X + (size_t)b * K * NP;
    const int wid = tid >> 6;
    const int lane = tid & 63;
    const int ln16 = lane & 15;
    const int quad = lane >> 4;
    const int wy = wid >> 1;
    const int wx = wid & 1;

    f32x4 acc[4][4];
    #pragma unroll
    for (int i = 0; i < 4; ++i)
        #pragma unroll
        for (int j = 0; j < 4; ++j)
            acc[i][j] = f32x4{0.f, 0.f, 0.f, 0.f};

    for (int k0 = 0; k0 < K; k0 += 32) {
        #pragma unroll
        for (int r = 0; r < 2; ++r) {
            int flat = tid + r * 256;
            int kk = flat >> 4;
            int nn = (flat & 15) * 8;
            uint4 v = *(const uint4*)(Xb + (size_t)(k0 + kk) * NP + n0 + nn);
            unsigned int* d = (unsigned int*)&Bs[kk][nn];
            d[0] = v.x; d[1] = v.y; d[2] = v.z; d[3] = v.w;
        }
        __syncthreads();

        bf16x8 afr[4];
        #pragma unroll
        for (int mt = 0; mt < 4; ++mt) {
            int m = m0 + wy * 64 + mt * 16 + ln16;
            uint4 v = *(const uint4*)(W + (size_t)m * K + k0 + quad * 8);
            afr[mt] = *(bf16x8*)&v;
        }
        bf16x8 bfr[4];
        #pragma unroll
        for (int nt = 0; nt < 4; ++nt) {
            int n = wx * 64 + nt * 16 + ln16;
            union { bf16x8 v; unsigned short u[8]; } tmp;
            #pragma unroll
            for (int j = 0; j < 8; ++j) tmp.u[j] = Bs[quad * 8 + j][n];
            bfr[nt] = tmp.v;
        }
        #pragma unroll
        for (int mt = 0; mt < 4; ++mt)
            #pragma unroll
            for (int nt = 0; nt < 4; ++nt)
                acc[mt][nt] = __builtin_amdgcn_mfma_f32_16x16x32_bf16(
                    afr[mt], bfr[nt], acc[mt][nt], 0, 0, 0);
        __syncthreads();
    }

    size_t outbase = (size_t)b * Cout * NP;
    #pragma unroll
    for (int mt = 0; mt < 4; ++mt) {
        int lr = wy * 16 + quad * 4;
        #pragma unroll
        for (int nt = 0; nt < 4; ++nt) {
            int nn = wx * 64 + nt * 16 + ln16;
            #pragma unroll
            for (int r = 0; r < 4; ++r)
                Stf[(lr + r) * 132 + nn] = acc[mt][nt][r];
        }
        __syncthreads();
        #pragma unroll
        for (int i = 0; i < 4; ++i) {
            int flat = tid + i * 256;
            int row = flat >> 5;
            int g = flat & 31;
            f32x4 v = *(const f32x4*)(&Stf[row * 132 + g * 4]);
            int absrow = m0 + (row >> 4) * 64 + mt * 16 + (row & 15);
            size_t idx = outbase + (size_t)absrow * NP + n0 + g * 4;
            union { uint2 u2; unsigned short u[4]; } rv;
            rv.u2 = *(const uint2*)(Res + idx);
            f32x4 o;
            #pragma unroll
            for (int k = 0; k < 4; ++k) o[k] = b2f(rv.u[k]) + v[k];
            *(f32x4*)(Out + idx) = o;
        }
        __syncthreads();
    }
}

// ---------- fused dw3x3 + fast-GELU gate ----------
__global__ __launch_bounds__(256)
void dwgelu_kernel(const unsigned short* __restrict__ hdn,
                   const unsigned short* __restrict__ w9,
                   unsigned short* __restrict__ g)
{
    int t = blockIdx.x * 256 + threadIdx.x;
    int xi = (t & 15) * 8;
    int y  = (t >> 4) & 127;
    int bc = t >> 11;
    int c  = bc & 255;
    int b  = bc >> 8;
    const unsigned short* base1 = hdn + ((size_t)b * 512 + c) * NP + y * 128 + xi;
    const unsigned short* base2 = base1 + (size_t)256 * NP;

    float w1[9], w2[9];
    #pragma unroll
    for (int i = 0; i < 9; ++i) {
        w1[i] = b2f(w9[c * 9 + i]);
        w2[i] = b2f(w9[(c + 256) * 9 + i]);
    }

    float a1[8], a2[8];
    dw8(base1, y, xi, w1, a1);
    dw8(base2, y, xi, w2, a2);

    union { uint4 v; unsigned short u[8]; } res;
    #pragma unroll
    for (int j = 0; j < 8; ++j) {
        float u = a1[j];
        float tt = u * (0.7978845608f + 0.0356774081f * u * u);
        float e = __expf(2.f * tt);
        float th = 1.f - 2.f / (e + 1.f);
        float ge = 0.5f * u * (1.f + th);
        res.u[j] = f2b(ge * a2[j]);
    }
    *(uint4*)(g + (size_t)bc * NP + y * 128 + xi) = res.v;
}

// ---------- pipeline ----------
struct Bufs {
    unsigned short* xmid;   // nb*C*NP bf16 (trunk after MDTA, channel-major)
    unsigned short* big;    // nb*512*NP bf16 channel-major (qkv1 / hdn)
    unsigned short* mid;    // nb*256*NP bf16 channel-major (gate out)
    float* Spart;           // nb*NH*32*256
    float* Npart;           // nb*NH*32*32
    unsigned short* W2;     // nb*128*128 bf16 (proj x blockdiag(P))
};

static void run_pipeline(const float* x_f32, float* out_f32,
                         const unsigned short* w,
                         const Bufs& B, int nb, hipStream_t stream)
{
    const unsigned short* ln1_w   = w + 0;
    const unsigned short* ln1_b   = w + 128;
    const unsigned short* temp    = w + 256;
    const unsigned short* qkv_p_w = w + 272;
    const unsigned short* qkv_d_w = w + 49424;
    const unsigned short* proj_w  = w + 52880;
    const unsigned short* ln2_w   = w + 69264;
    const unsigned short* ln2_b   = w + 69392;
    const unsigned short* g1_w    = w + 69520;
    const unsigned short* gd_w    = w + 135056;
    const unsigned short* g2_w    = w + 139664;

    // ---- MDTA ----
    lngemm_kernel<384><<<dim3(NP / 128, nb), 256, 0, stream>>>(x_f32, ln1_w, ln1_b, qkv_p_w, B.big);
    dwqkgram_kernel<<<dim3(NH, nb, 32), 256, 0, stream>>>(B.big, qkv_d_w, B.Spart, B.Npart);
    softwp_kernel<<<nb * NH, 256, 0, stream>>>(B.Spart, B.Npart, temp, proj_w, B.W2);
    projln_kernel<<<dim3(NP / 128, nb), 256, 0, stream>>>(B.W2, B.big, qkv_d_w, x_f32, B.xmid);

    // ---- GDFN ----
    lngemm2_kernel<512><<<dim3(NP / 128, nb), 256, 0, stream>>>(B.xmid, ln2_w, ln2_b, g1_w, B.big);
    dwgelu_kernel<<<nb * 256 * NP / 2048, 256, 0, stream>>>(B.big, gd_w, B.mid);
    gemm_pconv<256><<<dim3(NP / 128, 1, nb), 256, 0, stream>>>(g2_w, B.mid, out_f32, B.xmid, 128);
}

extern "C" void kernel_launch(void* const* d_in, const int* in_sizes, int n_in,
                              void* d_out, int out_size, void* d_ws, size_t ws_size,
                              hipStream_t stream)
{
    (void)in_sizes; (void)n_in; (void)out_size;
    const float* x = (const float*)d_in[0];
    char* ws = (char*)d_ws;

    size_t off = 0;
    unsigned short* wpack = (unsigned short*)(ws + off);
    off += (size_t)kWTotal * 2;
    off = (off + 255) & ~(size_t)255;
    size_t header = off;

    auto layout = [&](int nb, size_t o, Bufs& B) -> size_t {
        B.xmid = (unsigned short*)(ws + o);  o += (size_t)nb * C * NP * 2;
        B.big  = (unsigned short*)(ws + o);  o += (size_t)nb * 512 * NP * 2;
        B.mid  = (unsigned short*)(ws + o);  o += (size_t)nb * 256 * NP * 2;
        B.Spart = (float*)(ws + o);          o += (size_t)nb * NH * 32 * 256 * 4;
        B.Npart = (float*)(ws + o);          o += (size_t)nb * NH * 32 * 32 * 4;
        B.W2   = (unsigned short*)(ws + o);  o += (size_t)nb * 128 * 128 * 2;
        return o;
    };

    Ptr11 P;
    for (int i = 0; i < 11; ++i) P.p[i] = (const float*)d_in[i + 1];
    cvt_w_kernel<<<dim3(256, 11), 256, 0, stream>>>(P, wpack);

    Bufs Bfull;
    size_t need_full = layout(4, header, Bfull);

    if (ws_size >= need_full) {
        run_pipeline(x, (float*)d_out, wpack, Bfull, 4, stream);
    } else {
        Bufs B1;
        layout(1, header, B1);
        for (int b = 0; b < 4; ++b) {
            run_pipeline(x + (size_t)b * C * NP,
                         (float*)d_out + (size_t)b * C * NP,
                         wpack, B1, 1, stream);
        }
    }
}